// Round 7
// baseline (1642.093 us; speedup 1.0000x reference)
//
#include <hip/hip_runtime.h>

#define NN 262144   // rows (embeddings)
#define DD 128      // dim
#define KK 512      // clusters
#define NITER 5

// LDS row stride (bf16 elems): 128+8 -> 272B (16B-aligned rows).
#define SKH 136

// VALU-fallback LDS strides (floats)
#define SE 132
#define SC 260
#define SS 129

// Ambiguity threshold for the bf16x3 approx argmax. Rigorous error bound:
// 3*2^-16*||e||*||c|| <= 6.6e-4. delta = 2e-3 > 2*eps. (round-2 verified)
#define DELTA 2e-3f

// ---- workspace layout ----
#define WS_A16_BYTES   (NN * 2)                       // u16 assigns
#define WS_SUMS_OFF    (WS_A16_BYTES)                 // 2048 x 128 f32 partials
#define WS_CNTS_OFF    (WS_SUMS_OFF + 2048 * DD * 4)  // 2048 i32 counts
#define WS_NEEDED      (WS_CNTS_OFF + 2048 * 4)       // = 1581056 (round-2 gate)
// Overlays INSIDE ws_sums (1 MB), no lifetime overlap per iteration:
//   flags: NN bytes @ WS_SUMS_OFF       (assign writes -> rescue reads)
//   CH/CL fragment-major @ WS_SUMS_OFF + NN (split writes -> assign reads)
#define WS_CH_OFF      (WS_SUMS_OFF + NN)
#define WS_CL_OFF      (WS_CH_OFF + KK * DD * 2)
// fast2: pre-split E planes (row-major bf16 hi / lo), written once, read-only.
#define WS_EH2_OFF     (WS_NEEDED)
#define WS_EL2_OFF     (WS_EH2_OFF + NN * DD * 2)
#define WS_NEEDED2     (WS_EL2_OFF + NN * DD * 2)     // same gate as rounds 5/6

using s8     = __attribute__((ext_vector_type(8))) short;   // 8 bf16 (4 VGPR)
using f32x4  = __attribute__((ext_vector_type(4))) float;
using f32x16 = __attribute__((ext_vector_type(16))) float;  // 32x32 MFMA acc

// RNE float -> bf16 bits (finite inputs only)
__device__ __forceinline__ unsigned f2bf(float x) {
    unsigned u = __float_as_uint(x);
    return (u + 0x7fffu + ((u >> 16) & 1u)) >> 16;
}

// split float4 into packed hi/lo bf16 pairs (x = hi + lo + O(2^-16 x))
__device__ __forceinline__ void split4(float4 v, uint2& h, uint2& s) {
    unsigned hx = f2bf(v.x), hy = f2bf(v.y), hz = f2bf(v.z), hw = f2bf(v.w);
    float rx = v.x - __uint_as_float(hx << 16);
    float ry = v.y - __uint_as_float(hy << 16);
    float rz = v.z - __uint_as_float(hz << 16);
    float rw = v.w - __uint_as_float(hw << 16);
    unsigned lx = f2bf(rx), ly = f2bf(ry), lz = f2bf(rz), lw = f2bf(rw);
    h.x = hx | (hy << 16); h.y = hz | (hw << 16);
    s.x = lx | (ly << 16); s.y = lz | (lw << 16);
}

// ---------------------------------------------------------------------------
// ONE-TIME: pre-split E into ROW-MAJOR bf16 hi/lo planes (round-6 verified).
// ---------------------------------------------------------------------------
__global__ __launch_bounds__(256) void presplit_e2_kernel(
    const float* __restrict__ E, unsigned short* __restrict__ EH2,
    unsigned short* __restrict__ EL2)
{
    const size_t j = (size_t)blockIdx.x * 256 + threadIdx.x;   // 0..NN*DD/8-1
    float4 v0 = *(const float4*)&E[j * 8];
    float4 v1 = *(const float4*)&E[j * 8 + 4];
    uint2 h0, s0, h1, s1;
    split4(v0, h0, s0); split4(v1, h1, s1);
    *(uint2*)((char*)EH2 + j * 16)     = h0;
    *(uint2*)((char*)EH2 + j * 16 + 8) = h1;
    *(uint2*)((char*)EL2 + j * 16)     = s0;
    *(uint2*)((char*)EL2 + j * 16 + 8) = s1;
}

// ---------------------------------------------------------------------------
// Per-iter split of C for the 32x32x16 B-fragment layout. For col, k:
//   unit = (col>>5)*8 + (k>>4);  lane = (col&31) + ((k>>3)&1)*32;  e = k&7
//   elem offset = unit*512 + lane*8 + e
// A wave's B read for (colgrp, kstep) is one contiguous 1KB segment.
// ---------------------------------------------------------------------------
__global__ __launch_bounds__(256) void split_c3_kernel(
    const float* __restrict__ C, unsigned short* __restrict__ CH,
    unsigned short* __restrict__ CL)
{
    int idx = blockIdx.x * 256 + threadIdx.x;      // 16384 float4s
    int col = idx >> 5;
    int k4  = (idx & 31) << 2;
    float4 v = *(const float4*)&C[(size_t)col * DD + k4];
    uint2 h, s;
    split4(v, h, s);
    int unit = (col >> 5) * 8 + (k4 >> 4);
    int lane = (col & 31) + ((k4 >> 3) & 1) * 32;
    int off  = unit * 512 + lane * 8 + (k4 & 7);
    *(uint2*)&CH[off] = h;
    *(uint2*)&CL[off] = s;
}

// ---------------------------------------------------------------------------
// FAST2 assign: bf16x3 GEMM on mfma_f32_32x32x16_bf16. 4 waves, each owns
// 32 rows x all 512 cols (4 chunks x 4 col-frags of 32). A from LDS-staged
// pre-split planes (memcpy staging); B streamed as 1KB wave-segments from
// CB layout above. Per-wave complete argmax -> no cross-wave merge, single
// barrier. C/D mapping: col=lane&31, row=(reg&3)+8*(reg>>2)+4*(lane>>5).
// Top-2 + DELTA flags + rescue keep exactness as in rounds 2-6.
// ---------------------------------------------------------------------------
__global__ __launch_bounds__(256, 2) void assign3_kernel(
    const unsigned short* __restrict__ EH2, const unsigned short* __restrict__ EL2,
    const unsigned short* __restrict__ CH, const unsigned short* __restrict__ CL,
    int* __restrict__ assignv, unsigned short* __restrict__ assign16,
    unsigned char* __restrict__ flags)
{
    __shared__ unsigned short lds[2 * 128 * SKH];   // 69632 B
    unsigned short* EH = lds;
    unsigned short* EL = lds + 128 * SKH;

    const int tid = threadIdx.x;
    const int l   = tid & 63;
    const int wid = tid >> 6;          // wave owns rows wid*32..+31
    const int j   = l & 31;            // A row / B col / D col within frag
    const int h   = l >> 5;            // k-octet half; D row offset 4*h
    const int r0  = blockIdx.x * 128;

    // ---- stage E tile: plain 16B copies from pre-split planes
    {
        const char* srcH = (const char*)EH2 + (size_t)r0 * 256;
        const char* srcL = (const char*)EL2 + (size_t)r0 * 256;
#pragma unroll
        for (int it = 0; it < 8; ++it) {
            int jj = it * 256 + tid;           // row=jj>>4, 16B-chunk=jj&15
            int row = jj >> 4, k16 = jj & 15;
            uint4 hh = *(const uint4*)(srcH + (size_t)jj * 16);
            uint4 ss = *(const uint4*)(srcL + (size_t)jj * 16);
            *(uint4*)((char*)&EH[row * SKH] + k16 * 16) = hh;
            *(uint4*)((char*)&EL[row * SKH] + k16 * 16) = ss;
        }
    }
    __syncthreads();

    float bv[16], sv[16];
    int   bk[16];
#pragma unroll
    for (int i = 0; i < 16; ++i) { bv[i] = -3.4e38f; sv[i] = -3.4e38f; bk[i] = 0; }

    const int aoff0 = (wid * 32 + j) * SKH + h * 8;   // elem offset base for A
    const int boff0 = l * 8;                          // per-lane B base (elems)

#pragma unroll
    for (int cc = 0; cc < 4; ++cc) {
        f32x16 acc[4];
#pragma unroll
        for (int cf = 0; cf < 4; ++cf)
#pragma unroll
            for (int r = 0; r < 16; ++r) acc[cf][r] = 0.f;

#pragma unroll
        for (int ks = 0; ks < 8; ++ks) {
            s8 ah = *(const s8*)&EH[aoff0 + ks * 16];
            s8 al = *(const s8*)&EL[aoff0 + ks * 16];
#pragma unroll
            for (int cf = 0; cf < 4; ++cf) {
                const int unit = (cc * 4 + cf) * 8 + ks;
                s8 bh = *(const s8*)&CH[unit * 512 + boff0];
                s8 bl = *(const s8*)&CL[unit * 512 + boff0];
                acc[cf] = __builtin_amdgcn_mfma_f32_32x32x16_bf16(
                    ah, bh, acc[cf], 0, 0, 0);
                acc[cf] = __builtin_amdgcn_mfma_f32_32x32x16_bf16(
                    ah, bl, acc[cf], 0, 0, 0);
                acc[cf] = __builtin_amdgcn_mfma_f32_32x32x16_bf16(
                    al, bh, acc[cf], 0, 0, 0);
            }
        }

        // fold chunk into per-lane running top-2. Per lane the column is
        // fixed per cf: kg = cc*128 + cf*32 + j (ascending over cf, cc).
#pragma unroll
        for (int cf = 0; cf < 4; ++cf) {
            const int kg = cc * 128 + cf * 32 + j;
#pragma unroll
            for (int r = 0; r < 16; ++r) {
                float v = acc[cf][r];
                if (v > bv[r]) { sv[r] = bv[r]; bv[r] = v; bk[r] = kg; }
                else           { sv[r] = fmaxf(sv[r], v); }
            }
        }
    }

    // cross-lane top-2 butterfly over the 32 column-lanes of each half
    // (lanes sharing h hold the same 16 rows; exact ties leave v1==v2 ->
    // flagged -> rescue resolves first-occurrence exactly).
#pragma unroll
    for (int r = 0; r < 16; ++r) {
        float v1 = bv[r], v2 = sv[r]; int k1 = bk[r];
#pragma unroll
        for (int m = 1; m <= 16; m <<= 1) {
            float ov = __shfl_xor(v1, m, 64);
            float os = __shfl_xor(v2, m, 64);
            int   ok = __shfl_xor(k1, m, 64);
            if (ov > v1) { v2 = fmaxf(v1, os); v1 = ov; k1 = ok; }
            else         { v2 = fmaxf(v2, ov); }
        }
        bv[r] = v1; sv[r] = v2; bk[r] = k1;
    }

    // epilogue: all 32 lanes of a half hold identical merged results for
    // their 16 rows; lane j==r writes row (r&3)+8*(r>>2)+4*h of its wave.
#pragma unroll
    for (int r = 0; r < 16; ++r) {
        if (j == r) {
            int rowg = r0 + wid * 32 + (r & 3) + 8 * (r >> 2) + 4 * h;
            assignv[rowg]  = bk[r];
            assign16[rowg] = (unsigned short)bk[r];
            flags[rowg]    = (bv[r] - sv[r] < DELTA) ? 1 : 0;
        }
    }
}

// ---------------------------------------------------------------------------
// Per-iter split of C into hi/lo, 16x16 fragment-major (fast-path fallback).
// ---------------------------------------------------------------------------
__global__ __launch_bounds__(256) void split_c_kernel(
    const float* __restrict__ C, unsigned short* __restrict__ CH,
    unsigned short* __restrict__ CL)
{
    int idx = blockIdx.x * 256 + threadIdx.x;      // 16384 float4s
    int col = idx >> 5;
    int k4  = (idx & 31) << 2;
    float4 v = *(const float4*)&C[(size_t)col * DD + k4];
    uint2 h, s;
    split4(v, h, s);
    int group = (col >> 4) * 4 + (k4 >> 5);
    int inner = ((k4 >> 3) & 3) * 16 + (col & 15);
    int off   = group * 512 + inner * 8 + (k4 & 7);
    *(uint2*)&CH[off] = h;
    *(uint2*)&CL[off] = s;
}

// ---------------------------------------------------------------------------
// Fallback fast assign (round-4 verified): split E in-kernel, B from CH/CL.
// ---------------------------------------------------------------------------
__global__ __launch_bounds__(256, 2) void assign_kernel(
    const float* __restrict__ E,
    const unsigned short* __restrict__ CH, const unsigned short* __restrict__ CL,
    int* __restrict__ assignv, unsigned short* __restrict__ assign16,
    unsigned char* __restrict__ flags)
{
    __shared__ unsigned short lds[2 * 128 * SKH];   // 69632 B
    unsigned short* EH = lds;
    unsigned short* EL = lds + 128 * SKH;

    const int tid = threadIdx.x;
    const int l   = tid & 63;
    const int wid = tid >> 6;
    const int wr  = wid >> 1;
    const int wc  = wid & 1;
    const int c   = l & 15;
    const int g   = l >> 4;
    const int r0  = blockIdx.x * 128;

#pragma unroll
    for (int it = 0; it < 16; ++it) {
        int idx = it * 256 + tid;
        int row = idx >> 5;
        int k4  = (idx & 31) << 2;
        float4 v = *(const float4*)&E[(size_t)(r0 + row) * DD + k4];
        uint2 h, s;
        split4(v, h, s);
        *(uint2*)&EH[row * SKH + k4] = h;
        *(uint2*)&EL[row * SKH + k4] = s;
    }
    __syncthreads();

    float bv[16], sv[16];
    int   bk[16];
#pragma unroll
    for (int i = 0; i < 16; ++i) { bv[i] = -3.4e38f; sv[i] = -3.4e38f; bk[i] = 0; }

    const int aoff0 = (wr * 64 + c) * SKH + g * 8;
    const int bbase = wc * 16 * 512 + l * 8;

    s8 bh[2][4], bl[2][4];
#pragma unroll
    for (int cf = 0; cf < 4; ++cf) {
        int off = bbase + (cf * 4) * 512;
        bh[0][cf] = *(const s8*)&CH[off];
        bl[0][cf] = *(const s8*)&CL[off];
    }

    f32x4 acc[4][4];

#pragma unroll
    for (int t = 0; t < 16; ++t) {
        const int cc  = t >> 2, kc = t & 3;
        const int cur = t & 1,  nxt = cur ^ 1;

        if (kc == 0) {
#pragma unroll
            for (int rf = 0; rf < 4; ++rf)
#pragma unroll
                for (int cf = 0; cf < 4; ++cf)
                    acc[rf][cf] = (f32x4){0.f, 0.f, 0.f, 0.f};
        }

        if (t < 15) {
            const int t1 = t + 1, cc1 = t1 >> 2, kc1 = t1 & 3;
#pragma unroll
            for (int cf = 0; cf < 4; ++cf) {
                int off = bbase + (cc1 * 32 + cf * 4 + kc1) * 512;
                bh[nxt][cf] = *(const s8*)&CH[off];
                bl[nxt][cf] = *(const s8*)&CL[off];
            }
        }

        s8 ah[4], al[4];
#pragma unroll
        for (int rf = 0; rf < 4; ++rf) {
            int off = aoff0 + rf * 16 * SKH + kc * 32;
            ah[rf] = *(const s8*)&EH[off];
            al[rf] = *(const s8*)&EL[off];
        }

#pragma unroll
        for (int rf = 0; rf < 4; ++rf)
#pragma unroll
            for (int cf = 0; cf < 4; ++cf) {
                acc[rf][cf] = __builtin_amdgcn_mfma_f32_16x16x32_bf16(
                    ah[rf], bh[cur][cf], acc[rf][cf], 0, 0, 0);
                acc[rf][cf] = __builtin_amdgcn_mfma_f32_16x16x32_bf16(
                    ah[rf], bl[cur][cf], acc[rf][cf], 0, 0, 0);
                acc[rf][cf] = __builtin_amdgcn_mfma_f32_16x16x32_bf16(
                    al[rf], bh[cur][cf], acc[rf][cf], 0, 0, 0);
            }

        if (kc == 3) {
            const int kbase = cc * 128 + wc * 64 + c;
#pragma unroll
            for (int rf = 0; rf < 4; ++rf)
#pragma unroll
                for (int i = 0; i < 4; ++i) {
                    const int sidx = rf * 4 + i;
#pragma unroll
                    for (int cf = 0; cf < 4; ++cf) {
                        float v = acc[rf][cf][i];
                        int  kg = kbase + cf * 16;
                        if (v > bv[sidx]) { sv[sidx] = bv[sidx]; bv[sidx] = v; bk[sidx] = kg; }
                        else              { sv[sidx] = fmaxf(sv[sidx], v); }
                    }
                }
        }
    }

#pragma unroll
    for (int s = 0; s < 16; ++s) {
        float v1 = bv[s], v2 = sv[s]; int k1 = bk[s];
#pragma unroll
        for (int m = 1; m <= 8; m <<= 1) {
            float ov = __shfl_xor(v1, m, 64);
            float os = __shfl_xor(v2, m, 64);
            int   ok = __shfl_xor(k1, m, 64);
            if (ov > v1) { v2 = fmaxf(v1, os); v1 = ov; k1 = ok; }
            else         { v2 = fmaxf(v2, ov); }
        }
        bv[s] = v1; sv[s] = v2; bk[s] = k1;
    }

    __syncthreads();
    float* mv = (float*)lds;
    int*   mk = (int*)lds + 256;
    float* ms = (float*)lds + 512;
    if (c == 0) {
#pragma unroll
        for (int rf = 0; rf < 4; ++rf)
#pragma unroll
            for (int i = 0; i < 4; ++i) {
                int row = wr * 64 + rf * 16 + g * 4 + i;
                mv[wc * 128 + row] = bv[rf * 4 + i];
                mk[wc * 128 + row] = bk[rf * 4 + i];
                ms[wc * 128 + row] = sv[rf * 4 + i];
            }
    }
    __syncthreads();
    if (tid < 128) {
        float v1 = mv[tid], v2 = ms[tid]; int k1 = mk[tid];
        float ov = mv[128 + tid], os = ms[128 + tid]; int ok = mk[128 + tid];
        if (ov > v1) { v2 = fmaxf(v1, os); v1 = ov; k1 = ok; }
        else         { v2 = fmaxf(v2, ov); }
        assignv[r0 + tid] = k1;
        assign16[r0 + tid] = (unsigned short)k1;
        flags[r0 + tid] = (v1 - v2 < DELTA) ? 1 : 0;
    }
}

// ---------------------------------------------------------------------------
// Rescue: exact fp32 re-argmax (first-occurrence) for flagged rows only.
// ---------------------------------------------------------------------------
__global__ __launch_bounds__(256) void rescue_kernel(
    const float* __restrict__ E, const float* __restrict__ C,
    const unsigned char* __restrict__ flags,
    int* __restrict__ assignv, unsigned short* __restrict__ assign16)
{
    __shared__ int   rows[128];
    __shared__ int   nf;
    __shared__ float ev[DD];
    __shared__ float rv[4];
    __shared__ int   rk[4];

    const int tid  = threadIdx.x;
    const int base = blockIdx.x * 128;

    if (tid == 0) nf = 0;
    __syncthreads();
    if (tid < 128 && flags[base + tid]) {
        int p = atomicAdd(&nf, 1);
        rows[p] = base + tid;
    }
    __syncthreads();
    const int n = nf;
    if (n == 0) return;

    for (int i = 0; i < n; ++i) {
        const int row = rows[i];
        if (tid < 32)
            *(float4*)&ev[tid * 4] = *(const float4*)&E[(size_t)row * DD + tid * 4];
        __syncthreads();

        float d0 = 0.f, d1 = 0.f;
        for (int q = 0; q < 32; ++q) {
            float4 e4 = *(const float4*)&ev[q * 4];
            float4 c0 = *(const float4*)&C[(size_t)tid * DD + q * 4];
            float4 c1 = *(const float4*)&C[(size_t)(tid + 256) * DD + q * 4];
            d0 = fmaf(e4.x, c0.x, d0); d0 = fmaf(e4.y, c0.y, d0);
            d0 = fmaf(e4.z, c0.z, d0); d0 = fmaf(e4.w, c0.w, d0);
            d1 = fmaf(e4.x, c1.x, d1); d1 = fmaf(e4.y, c1.y, d1);
            d1 = fmaf(e4.z, c1.z, d1); d1 = fmaf(e4.w, c1.w, d1);
        }
        float v = (d0 >= d1) ? d0 : d1;
        int   k = (d0 >= d1) ? tid : tid + 256;
#pragma unroll
        for (int m = 1; m <= 32; m <<= 1) {
            float ov = __shfl_xor(v, m, 64);
            int   ok = __shfl_xor(k, m, 64);
            if (ov > v || (ov == v && ok < k)) { v = ov; k = ok; }
        }
        if ((tid & 63) == 0) { rv[tid >> 6] = v; rk[tid >> 6] = k; }
        __syncthreads();
        if (tid == 0) {
            float bv2 = rv[0]; int bk2 = rk[0];
#pragma unroll
            for (int w = 1; w < 4; ++w)
                if (rv[w] > bv2 || (rv[w] == bv2 && rk[w] < bk2)) { bv2 = rv[w]; bk2 = rk[w]; }
            assignv[row] = bk2;
            assign16[row] = (unsigned short)bk2;
        }
        __syncthreads();
    }
}

// ---------------------------------------------------------------------------
// Fallback assignment (pure fp32 VALU, verified) for tiny ws.
// ---------------------------------------------------------------------------
__global__ __launch_bounds__(256, 2) void assign_valu_kernel(
    const float* __restrict__ E, const float* __restrict__ C,
    int* __restrict__ assignv, unsigned short* __restrict__ assign16)
{
    __shared__ float smem[32 * SE + 32 * SC];
    float* ET = smem;
    float* CT = smem + 32 * SE;
    float* sval = smem;
    int*   sidx = ((int*)smem) + 32 * SS;

    const int tid = threadIdx.x;
    const int tx  = tid & 31;
    const int ty  = tid >> 5;
    const int r0  = blockIdx.x * 128;

    float bbv = 0.f;
    int   bbk = 0;

    for (int chunk = 0; chunk < 2; ++chunk) {
        const int k0 = chunk * 256;
        float acc[16][8];
#pragma unroll
        for (int i = 0; i < 16; ++i)
#pragma unroll
            for (int j = 0; j < 8; ++j) acc[i][j] = 0.f;

        for (int sub = 0; sub < 4; ++sub) {
            const int d0 = sub * 32;
            __syncthreads();
#pragma unroll
            for (int it = 0; it < 4; ++it) {
                int idx = tid + it * 256;
                int r = idx >> 3, q = idx & 7;
                float4 v = *(const float4*)&E[(r0 + r) * DD + d0 + q * 4];
                ET[(q * 4 + 0) * SE + r] = v.x;
                ET[(q * 4 + 1) * SE + r] = v.y;
                ET[(q * 4 + 2) * SE + r] = v.z;
                ET[(q * 4 + 3) * SE + r] = v.w;
            }
#pragma unroll
            for (int it = 0; it < 8; ++it) {
                int idx = tid + it * 256;
                int k = idx >> 3, q = idx & 7;
                float4 v = *(const float4*)&C[(k0 + k) * DD + d0 + q * 4];
                CT[(q * 4 + 0) * SC + k] = v.x;
                CT[(q * 4 + 1) * SC + k] = v.y;
                CT[(q * 4 + 2) * SC + k] = v.z;
                CT[(q * 4 + 3) * SC + k] = v.w;
            }
            __syncthreads();
#pragma unroll 4
            for (int d = 0; d < 32; ++d) {
                float4 a0 = *(const float4*)&ET[d * SE + ty * 16];
                float4 a1 = *(const float4*)&ET[d * SE + ty * 16 + 4];
                float4 a2 = *(const float4*)&ET[d * SE + ty * 16 + 8];
                float4 a3 = *(const float4*)&ET[d * SE + ty * 16 + 12];
                float4 b0 = *(const float4*)&CT[d * SC + tx * 4];
                float4 b1 = *(const float4*)&CT[d * SC + 128 + tx * 4];
                float ra[16] = {a0.x, a0.y, a0.z, a0.w, a1.x, a1.y, a1.z, a1.w,
                                a2.x, a2.y, a2.z, a2.w, a3.x, a3.y, a3.z, a3.w};
                float rb[8]  = {b0.x, b0.y, b0.z, b0.w, b1.x, b1.y, b1.z, b1.w};
#pragma unroll
                for (int i = 0; i < 16; ++i)
#pragma unroll
                    for (int j = 0; j < 8; ++j)
                        acc[i][j] = fmaf(ra[i], rb[j], acc[i][j]);
            }
        }
        __syncthreads();

#pragma unroll
        for (int i = 0; i < 16; ++i) {
            float bv = acc[i][0]; int bj = 0;
#pragma unroll
            for (int j = 1; j < 8; ++j)
                if (acc[i][j] > bv) { bv = acc[i][j]; bj = j; }
            int row = ty * 16 + i;
            int gk = k0 + ((bj < 4) ? (tx * 4 + bj) : (128 + tx * 4 + (bj - 4)));
            sval[tx * SS + row] = bv;
            sidx[tx * SS + row] = gk;
        }
        __syncthreads();
        if (tid < 128) {
            float bv = sval[tid]; int bi = sidx[tid];
            for (int t = 1; t < 32; ++t) {
                float v = sval[t * SS + tid];
                int   x = sidx[t * SS + tid];
                if (v > bv || (v == bv && x < bi)) { bv = v; bi = x; }
            }
            if (chunk == 0 || bv > bbv || (bv == bbv && bi < bbk)) {
                bbv = bv; bbk = bi;
            }
        }
    }
    if (tid < 128) {
        assignv[r0 + tid] = bbk;
        if (assign16) assign16[r0 + tid] = (unsigned short)bbk;
    }
}

// ---------------------------------------------------------------------------
// Fast M-step, phase 1: 2048 blocks = 4 per cluster. Deterministic.
// ---------------------------------------------------------------------------
__global__ __launch_bounds__(256) void update_partial_kernel(
    const float* __restrict__ E, const unsigned short* __restrict__ assign16,
    float* __restrict__ ws_sums, int* __restrict__ ws_cnts)
{
    const int b   = blockIdx.x;
    const int k   = b >> 2;
    const int qtr = b & 3;

    __shared__ float acc[4][DD];
    __shared__ int   cnts[4];

    const int tid  = threadIdx.x;
    const int w    = tid >> 6;
    const int lane = tid & 63;

    float a0 = 0.f, a1 = 0.f;
    int cnt = 0;
    const int wbase = qtr * (NN / 4) + w * (NN / 16);

    for (int it = 0; it < (NN / 16) / 512; ++it) {
        const int off = wbase + it * 512;
        uint4 p = *(const uint4*)&assign16[off + lane * 8];
        unsigned v[4] = {p.x, p.y, p.z, p.w};
#pragma unroll
        for (int h = 0; h < 4; ++h) {
            int lo = (int)(v[h] & 0xffffu);
            int hi = (int)(v[h] >> 16);
            unsigned long long mlo = __ballot(lo == k);
            unsigned long long mhi = __ballot(hi == k);
            cnt += (int)__popcll(mlo) + (int)__popcll(mhi);
            while (mlo) {
                int b2 = __ffsll((long long)mlo) - 1; mlo &= mlo - 1;
                int row = off + b2 * 8 + h * 2;
                float2 e = *(const float2*)&E[(size_t)row * DD + lane * 2];
                a0 += e.x; a1 += e.y;
            }
            while (mhi) {
                int b2 = __ffsll((long long)mhi) - 1; mhi &= mhi - 1;
                int row = off + b2 * 8 + h * 2 + 1;
                float2 e = *(const float2*)&E[(size_t)row * DD + lane * 2];
                a0 += e.x; a1 += e.y;
            }
        }
    }
    acc[w][lane * 2]     = a0;
    acc[w][lane * 2 + 1] = a1;
    if (lane == 0) cnts[w] = cnt;
    __syncthreads();
    if (tid < DD)
        ws_sums[(size_t)b * DD + tid] = acc[0][tid] + acc[1][tid] + acc[2][tid] + acc[3][tid];
    if (tid == 0)
        ws_cnts[b] = cnts[0] + cnts[1] + cnts[2] + cnts[3];
}

// ---------------------------------------------------------------------------
// Fast M-step, phase 2: combine 4 partials, mean, L2-normalize.
// ---------------------------------------------------------------------------
__global__ __launch_bounds__(128) void update_combine_kernel(
    const float* __restrict__ ws_sums, const int* __restrict__ ws_cnts,
    float* __restrict__ C)
{
    const int k = blockIdx.x, t = threadIdx.x;
    __shared__ float red[2];
    const int w = t >> 6, lane = t & 63;

    float s = ws_sums[(size_t)(4 * k + 0) * DD + t]
            + ws_sums[(size_t)(4 * k + 1) * DD + t]
            + ws_sums[(size_t)(4 * k + 2) * DD + t]
            + ws_sums[(size_t)(4 * k + 3) * DD + t];
    int cnt = ws_cnts[4 * k] + ws_cnts[4 * k + 1] + ws_cnts[4 * k + 2] + ws_cnts[4 * k + 3];
    float m = (cnt > 0) ? s / (float)cnt : C[k * DD + t];

    float sq = m * m;
#pragma unroll
    for (int o = 32; o > 0; o >>= 1) sq += __shfl_down(sq, o, 64);
    if (lane == 0) red[w] = sq;
    __syncthreads();
    float nrm = fmaxf(sqrtf(red[0] + red[1]), 1e-12f);
    C[k * DD + t] = m / nrm;
}

// ---------------------------------------------------------------------------
// Fallback M-step (no d_ws usage).
// ---------------------------------------------------------------------------
__global__ __launch_bounds__(256) void update_kernel(
    const float* __restrict__ E, const int* __restrict__ assignv,
    float* __restrict__ C)
{
    const int k = blockIdx.x;
    __shared__ float acc[4][DD];
    __shared__ int   cnts[4];
    __shared__ float red[4];

    const int tid  = threadIdx.x;
    const int w    = tid >> 6;
    const int lane = tid & 63;

    float a0 = 0.f, a1 = 0.f;
    int cnt = 0;
    const int per_wave = NN / 4;
    const int base = w * per_wave;

    for (int it = 0; it < per_wave / 256; ++it) {
        const int off = base + it * 256;
        int4 as = *(const int4*)&assignv[off + lane * 4];
        int av[4] = {as.x, as.y, as.z, as.w};
#pragma unroll
        for (int ci = 0; ci < 4; ++ci) {
            unsigned long long m = __ballot(av[ci] == k);
            cnt += (int)__popcll(m);
            while (m) {
                int b = __ffsll((long long)m) - 1;
                m &= m - 1;
                int r = off + b * 4 + ci;
                float2 v = *(const float2*)&E[r * DD + lane * 2];
                a0 += v.x; a1 += v.y;
            }
        }
    }
    acc[w][lane * 2]     = a0;
    acc[w][lane * 2 + 1] = a1;
    if (lane == 0) cnts[w] = cnt;
    __syncthreads();

    float m = 0.f;
    const int ctot = cnts[0] + cnts[1] + cnts[2] + cnts[3];
    if (tid < DD) {
        float s = acc[0][tid] + acc[1][tid] + acc[2][tid] + acc[3][tid];
        m = (ctot > 0) ? s / (float)ctot : C[k * DD + tid];
    }
    float sq = m * m;
#pragma unroll
    for (int o = 32; o > 0; o >>= 1) sq += __shfl_down(sq, o, 64);
    if (lane == 0) red[w] = sq;
    __syncthreads();
    if (tid < DD) {
        float nrm = fmaxf(sqrtf(red[0] + red[1]), 1e-12f);
        C[k * DD + tid] = m / nrm;
    }
}

__global__ void finalize_kernel(float* __restrict__ out)
{
    int i = blockIdx.x * 256 + threadIdx.x;
    if (i < NN) {
        int a = ((const int*)out)[i];
        out[i] = (float)a;
    }
}

extern "C" void kernel_launch(void* const* d_in, const int* in_sizes, int n_in,
                              void* d_out, int out_size, void* d_ws, size_t ws_size,
                              hipStream_t stream)
{
    (void)in_sizes; (void)n_in; (void)out_size;

    const float* E  = (const float*)d_in[0];
    const float* C0 = (const float*)d_in[1];
    // num_iters (d_in[2]) is a fixed scalar = 5; hardcoded (graph-safe).

    float* out     = (float*)d_out;
    float* C       = out + NN;        // centroids in d_out tail
    int*   assignv = (int*)out;       // assign ints in d_out head

    const bool fast  = (ws_size >= (size_t)WS_NEEDED);
    const bool fast2 = (ws_size >= (size_t)WS_NEEDED2);
    unsigned short* assign16 = fast ? (unsigned short*)d_ws : nullptr;
    float* ws_sums = fast ? (float*)((char*)d_ws + WS_SUMS_OFF) : nullptr;
    int*   ws_cnts = fast ? (int*)((char*)d_ws + WS_CNTS_OFF) : nullptr;
    unsigned char* flags = fast ? (unsigned char*)d_ws + WS_SUMS_OFF : nullptr;
    unsigned short* CH = fast ? (unsigned short*)((char*)d_ws + WS_CH_OFF) : nullptr;
    unsigned short* CL = fast ? (unsigned short*)((char*)d_ws + WS_CL_OFF) : nullptr;
    unsigned short* EH2 = fast2 ? (unsigned short*)((char*)d_ws + WS_EH2_OFF) : nullptr;
    unsigned short* EL2 = fast2 ? (unsigned short*)((char*)d_ws + WS_EL2_OFF) : nullptr;

    hipMemcpyAsync(C, C0, (size_t)KK * DD * sizeof(float),
                   hipMemcpyDeviceToDevice, stream);

    if (fast2)
        presplit_e2_kernel<<<NN * DD / 8 / 256, 256, 0, stream>>>(E, EH2, EL2);

    for (int it = 0; it < NITER; ++it) {
        if (fast2) {
            split_c3_kernel<<<KK * DD / 4 / 256, 256, 0, stream>>>(C, CH, CL);
            assign3_kernel<<<NN / 128, 256, 0, stream>>>(EH2, EL2, CH, CL,
                                                         assignv, assign16, flags);
            rescue_kernel<<<NN / 128, 256, 0, stream>>>(E, C, flags, assignv, assign16);
            update_partial_kernel<<<2048, 256, 0, stream>>>(E, assign16, ws_sums, ws_cnts);
            update_combine_kernel<<<KK, 128, 0, stream>>>(ws_sums, ws_cnts, C);
        } else if (fast) {
            split_c_kernel<<<KK * DD / 4 / 256, 256, 0, stream>>>(C, CH, CL);
            assign_kernel<<<NN / 128, 256, 0, stream>>>(E, CH, CL, assignv, assign16, flags);
            rescue_kernel<<<NN / 128, 256, 0, stream>>>(E, C, flags, assignv, assign16);
            update_partial_kernel<<<2048, 256, 0, stream>>>(E, assign16, ws_sums, ws_cnts);
            update_combine_kernel<<<KK, 128, 0, stream>>>(ws_sums, ws_cnts, C);
        } else {
            assign_valu_kernel<<<NN / 128, 256, 0, stream>>>(E, C, assignv, nullptr);
            update_kernel<<<KK, 256, 0, stream>>>(E, assignv, C);
        }
    }
    finalize_kernel<<<(NN + 255) / 256, 256, 0, stream>>>(out);
}

// Round 8
// 1371.029 us; speedup vs baseline: 1.1977x; 1.1977x over previous
//
#include <hip/hip_runtime.h>

#define NN 262144   // rows (embeddings)
#define DD 128      // dim
#define KK 512      // clusters
#define NITER 5

// LDS row stride (bf16 elems) for fallback assign
#define SKH 136

// VALU-fallback LDS strides (floats)
#define SE 132
#define SC 260
#define SS 129

// Ambiguity threshold for the bf16x3 approx argmax. Rigorous error bound:
// 3*2^-16*||e||*||c|| <= 6.6e-4. delta = 2e-3 > 2*eps. (round-2 verified)
#define DELTA 2e-3f

// ---- workspace layout ----
#define WS_A16_BYTES   (NN * 2)                       // u16 assigns
#define WS_SUMS_OFF    (WS_A16_BYTES)                 // 2048 x 128 f32 partials
#define WS_CNTS_OFF    (WS_SUMS_OFF + 2048 * DD * 4)  // 2048 i32 counts
#define WS_NEEDED      (WS_CNTS_OFF + 2048 * 4)       // = 1581056 (round-2 gate)
// Overlays INSIDE ws_sums (1 MB), no lifetime overlap per iteration:
//   flags: NN bytes @ WS_SUMS_OFF       (assign writes -> rescue reads)
//   CH/CL fragment-major @ WS_SUMS_OFF + NN (split writes -> assign reads)
#define WS_CH_OFF      (WS_SUMS_OFF + NN)
#define WS_CL_OFF      (WS_CH_OFF + KK * DD * 2)
// fast2: pre-split E in 32-row-wave fragment-major units (EAB3).
// unit u = g32*8 + ks (g32 = row>>5, ks = k>>4). Byte layout per unit (2KB):
//   hi: lane*16 (lane = (row&31) + 32*((k>>3)&1)), lo: 1024 + lane*16.
// Wave g32's 16 A loads are contiguous 1KB segments at u*2048 (+1024).
#define WS_EAB3_OFF    (WS_NEEDED)
#define WS_EAB3_BYTES  (NN * DD * 4)                  // 134217728
#define WS_NEEDED2     (WS_EAB3_OFF + WS_EAB3_BYTES)  // same gate as rounds 5-7

using s8     = __attribute__((ext_vector_type(8))) short;   // 8 bf16 (4 VGPR)
using f32x4  = __attribute__((ext_vector_type(4))) float;
using f32x16 = __attribute__((ext_vector_type(16))) float;  // 32x32 MFMA acc

// RNE float -> bf16 bits (finite inputs only)
__device__ __forceinline__ unsigned f2bf(float x) {
    unsigned u = __float_as_uint(x);
    return (u + 0x7fffu + ((u >> 16) & 1u)) >> 16;
}

// split float4 into packed hi/lo bf16 pairs (x = hi + lo + O(2^-16 x))
__device__ __forceinline__ void split4(float4 v, uint2& h, uint2& s) {
    unsigned hx = f2bf(v.x), hy = f2bf(v.y), hz = f2bf(v.z), hw = f2bf(v.w);
    float rx = v.x - __uint_as_float(hx << 16);
    float ry = v.y - __uint_as_float(hy << 16);
    float rz = v.z - __uint_as_float(hz << 16);
    float rw = v.w - __uint_as_float(hw << 16);
    unsigned lx = f2bf(rx), ly = f2bf(ry), lz = f2bf(rz), lw = f2bf(rw);
    h.x = hx | (hy << 16); h.y = hz | (hw << 16);
    s.x = lx | (ly << 16); s.y = lz | (lw << 16);
}

// ---------------------------------------------------------------------------
// ONE-TIME: pre-split E into EAB3 (32-row wave units). Wave u: lane l reads
// E[g32*32+(l&31)][ks*16+(l>>5)*8 .. +7]; writes 1KB hi + 1KB lo coalesced.
// Contents per lane identical to round-7's verified LDS read pattern.
// ---------------------------------------------------------------------------
__global__ __launch_bounds__(256) void presplit_e3_kernel(
    const float* __restrict__ E, unsigned short* __restrict__ EAB)
{
    const int u   = blockIdx.x * 4 + (threadIdx.x >> 6);  // 0..65535
    const int l   = threadIdx.x & 63;
    const int g32 = u >> 3, ks = u & 7;
    const int row = g32 * 32 + (l & 31);
    const int k0  = ks * 16 + (l >> 5) * 8;
    float4 v0 = *(const float4*)&E[(size_t)row * DD + k0];
    float4 v1 = *(const float4*)&E[(size_t)row * DD + k0 + 4];
    uint2 h0, s0, h1, s1;
    split4(v0, h0, s0); split4(v1, h1, s1);
    size_t base = (size_t)u * 2048 + l * 16;
    *(uint2*)((char*)EAB + base)        = h0;
    *(uint2*)((char*)EAB + base + 8)    = h1;
    *(uint2*)((char*)EAB + base + 1024) = s0;
    *(uint2*)((char*)EAB + base + 1032) = s1;
}

// ---------------------------------------------------------------------------
// Per-iter split of C for the 32x32x16 B-fragment layout (round-7 verified).
// ---------------------------------------------------------------------------
__global__ __launch_bounds__(256) void split_c3_kernel(
    const float* __restrict__ C, unsigned short* __restrict__ CH,
    unsigned short* __restrict__ CL)
{
    int idx = blockIdx.x * 256 + threadIdx.x;      // 16384 float4s
    int col = idx >> 5;
    int k4  = (idx & 31) << 2;
    float4 v = *(const float4*)&C[(size_t)col * DD + k4];
    uint2 h, s;
    split4(v, h, s);
    int unit = (col >> 5) * 8 + (k4 >> 4);
    int lane = (col & 31) + ((k4 >> 3) & 1) * 32;
    int off  = unit * 512 + lane * 8 + (k4 & 7);
    *(uint2*)&CH[off] = h;
    *(uint2*)&CL[off] = s;
}

// ---------------------------------------------------------------------------
// FAST2 assign: bf16x3 GEMM on mfma_f32_32x32x16_bf16, LDS-FREE.
// 4 waves/block; wave wid owns rows g32=blk*4+wid (32 rows x all 512 cols).
// A tile (hi+lo, 16KB/wave) loaded ONCE into 64 VGPRs from EAB3 as 16
// contiguous 1KB wave-segments, reused across all 4 col-chunks. B streamed
// from CB with a one-step register double-buffer (round-6-verified pattern).
// No barriers anywhere. Fold/butterfly/epilogue identical to round-7
// verified assign3 (C/D map: col=lane&31, row=(reg&3)+8*(reg>>2)+4*(lane>>5)).
// ---------------------------------------------------------------------------
__global__ __launch_bounds__(256, 2) void assign4_kernel(
    const unsigned short* __restrict__ EAB,
    const unsigned short* __restrict__ CH, const unsigned short* __restrict__ CL,
    int* __restrict__ assignv, unsigned short* __restrict__ assign16,
    unsigned char* __restrict__ flags)
{
    const int tid = threadIdx.x;
    const int l   = tid & 63;
    const int wid = tid >> 6;
    const int j   = l & 31;            // A row / B col / D col within frag
    const int h   = l >> 5;            // k-octet half; D row offset 4*h
    const int r0  = blockIdx.x * 128;
    const int g32 = blockIdx.x * 4 + wid;

    // ---- load this wave's entire A tile into registers (16 x 1KB segments)
    const char* Abase = (const char*)EAB + (size_t)g32 * 16384 + l * 16;
    s8 Ah[8], Al[8];
#pragma unroll
    for (int ks = 0; ks < 8; ++ks) {
        Ah[ks] = *(const s8*)(Abase + ks * 2048);
        Al[ks] = *(const s8*)(Abase + ks * 2048 + 1024);
    }

    float bv[16], sv[16];
    int   bk[16];
#pragma unroll
    for (int i = 0; i < 16; ++i) { bv[i] = -3.4e38f; sv[i] = -3.4e38f; bk[i] = 0; }

    const int boff0 = l * 8;           // per-lane B base (elems)

    s8 bh[2][4], bl[2][4];             // B double buffer over t
#pragma unroll
    for (int cf = 0; cf < 4; ++cf) {   // preload t=0 (cc=0, ks=0)
        bh[0][cf] = *(const s8*)&CH[(cf * 8) * 512 + boff0];
        bl[0][cf] = *(const s8*)&CL[(cf * 8) * 512 + boff0];
    }

    f32x16 acc[4];

#pragma unroll
    for (int t = 0; t < 32; ++t) {
        const int cc  = t >> 3, ks = t & 7;
        const int cur = t & 1,  nxt = cur ^ 1;

        if (ks == 0) {
#pragma unroll
            for (int cf = 0; cf < 4; ++cf)
#pragma unroll
                for (int r = 0; r < 16; ++r) acc[cf][r] = 0.f;
        }

        // prefetch next step's B fragments (static buffer index after unroll)
        if (t < 31) {
            const int t1 = t + 1, cc1 = t1 >> 3, ks1 = t1 & 7;
#pragma unroll
            for (int cf = 0; cf < 4; ++cf) {
                const int unit = (cc1 * 4 + cf) * 8 + ks1;
                bh[nxt][cf] = *(const s8*)&CH[unit * 512 + boff0];
                bl[nxt][cf] = *(const s8*)&CL[unit * 512 + boff0];
            }
        }

#pragma unroll
        for (int cf = 0; cf < 4; ++cf) {
            acc[cf] = __builtin_amdgcn_mfma_f32_32x32x16_bf16(
                Ah[ks], bh[cur][cf], acc[cf], 0, 0, 0);
            acc[cf] = __builtin_amdgcn_mfma_f32_32x32x16_bf16(
                Ah[ks], bl[cur][cf], acc[cf], 0, 0, 0);
            acc[cf] = __builtin_amdgcn_mfma_f32_32x32x16_bf16(
                Al[ks], bh[cur][cf], acc[cf], 0, 0, 0);
        }

        // fold chunk into per-lane running top-2 (ascending k: cf inner, cc outer)
        if (ks == 7) {
#pragma unroll
            for (int cf = 0; cf < 4; ++cf) {
                const int kg = cc * 128 + cf * 32 + j;
#pragma unroll
                for (int r = 0; r < 16; ++r) {
                    float v = acc[cf][r];
                    if (v > bv[r]) { sv[r] = bv[r]; bv[r] = v; bk[r] = kg; }
                    else           { sv[r] = fmaxf(sv[r], v); }
                }
            }
        }
    }

    // cross-lane top-2 butterfly over the 32 column-lanes of each half
#pragma unroll
    for (int r = 0; r < 16; ++r) {
        float v1 = bv[r], v2 = sv[r]; int k1 = bk[r];
#pragma unroll
        for (int m = 1; m <= 16; m <<= 1) {
            float ov = __shfl_xor(v1, m, 64);
            float os = __shfl_xor(v2, m, 64);
            int   ok = __shfl_xor(k1, m, 64);
            if (ov > v1) { v2 = fmaxf(v1, os); v1 = ov; k1 = ok; }
            else         { v2 = fmaxf(v2, ov); }
        }
        bv[r] = v1; sv[r] = v2; bk[r] = k1;
    }

    // epilogue: lane j==r writes row (r&3)+8*(r>>2)+4*h of its wave's 32 rows
#pragma unroll
    for (int r = 0; r < 16; ++r) {
        if (j == r) {
            int rowg = r0 + wid * 32 + (r & 3) + 8 * (r >> 2) + 4 * h;
            assignv[rowg]  = bk[r];
            assign16[rowg] = (unsigned short)bk[r];
            flags[rowg]    = (bv[r] - sv[r] < DELTA) ? 1 : 0;
        }
    }
}

// ---------------------------------------------------------------------------
// Per-iter split of C into hi/lo, 16x16 fragment-major (fast-path fallback).
// ---------------------------------------------------------------------------
__global__ __launch_bounds__(256) void split_c_kernel(
    const float* __restrict__ C, unsigned short* __restrict__ CH,
    unsigned short* __restrict__ CL)
{
    int idx = blockIdx.x * 256 + threadIdx.x;      // 16384 float4s
    int col = idx >> 5;
    int k4  = (idx & 31) << 2;
    float4 v = *(const float4*)&C[(size_t)col * DD + k4];
    uint2 h, s;
    split4(v, h, s);
    int group = (col >> 4) * 4 + (k4 >> 5);
    int inner = ((k4 >> 3) & 3) * 16 + (col & 15);
    int off   = group * 512 + inner * 8 + (k4 & 7);
    *(uint2*)&CH[off] = h;
    *(uint2*)&CL[off] = s;
}

// ---------------------------------------------------------------------------
// Fallback fast assign (round-4 verified): split E in-kernel, B from CH/CL.
// ---------------------------------------------------------------------------
__global__ __launch_bounds__(256, 2) void assign_kernel(
    const float* __restrict__ E,
    const unsigned short* __restrict__ CH, const unsigned short* __restrict__ CL,
    int* __restrict__ assignv, unsigned short* __restrict__ assign16,
    unsigned char* __restrict__ flags)
{
    __shared__ unsigned short lds[2 * 128 * SKH];   // 69632 B
    unsigned short* EH = lds;
    unsigned short* EL = lds + 128 * SKH;

    const int tid = threadIdx.x;
    const int l   = tid & 63;
    const int wid = tid >> 6;
    const int wr  = wid >> 1;
    const int wc  = wid & 1;
    const int c   = l & 15;
    const int g   = l >> 4;
    const int r0  = blockIdx.x * 128;

#pragma unroll
    for (int it = 0; it < 16; ++it) {
        int idx = it * 256 + tid;
        int row = idx >> 5;
        int k4  = (idx & 31) << 2;
        float4 v = *(const float4*)&E[(size_t)(r0 + row) * DD + k4];
        uint2 h, s;
        split4(v, h, s);
        *(uint2*)&EH[row * SKH + k4] = h;
        *(uint2*)&EL[row * SKH + k4] = s;
    }
    __syncthreads();

    float bv[16], sv[16];
    int   bk[16];
#pragma unroll
    for (int i = 0; i < 16; ++i) { bv[i] = -3.4e38f; sv[i] = -3.4e38f; bk[i] = 0; }

    const int aoff0 = (wr * 64 + c) * SKH + g * 8;
    const int bbase = wc * 16 * 512 + l * 8;

    s8 bh[2][4], bl[2][4];
#pragma unroll
    for (int cf = 0; cf < 4; ++cf) {
        int off = bbase + (cf * 4) * 512;
        bh[0][cf] = *(const s8*)&CH[off];
        bl[0][cf] = *(const s8*)&CL[off];
    }

    f32x4 acc[4][4];

#pragma unroll
    for (int t = 0; t < 16; ++t) {
        const int cc  = t >> 2, kc = t & 3;
        const int cur = t & 1,  nxt = cur ^ 1;

        if (kc == 0) {
#pragma unroll
            for (int rf = 0; rf < 4; ++rf)
#pragma unroll
                for (int cf = 0; cf < 4; ++cf)
                    acc[rf][cf] = (f32x4){0.f, 0.f, 0.f, 0.f};
        }

        if (t < 15) {
            const int t1 = t + 1, cc1 = t1 >> 2, kc1 = t1 & 3;
#pragma unroll
            for (int cf = 0; cf < 4; ++cf) {
                int off = bbase + (cc1 * 32 + cf * 4 + kc1) * 512;
                bh[nxt][cf] = *(const s8*)&CH[off];
                bl[nxt][cf] = *(const s8*)&CL[off];
            }
        }

        s8 ah[4], al[4];
#pragma unroll
        for (int rf = 0; rf < 4; ++rf) {
            int off = aoff0 + rf * 16 * SKH + kc * 32;
            ah[rf] = *(const s8*)&EH[off];
            al[rf] = *(const s8*)&EL[off];
        }

#pragma unroll
        for (int rf = 0; rf < 4; ++rf)
#pragma unroll
            for (int cf = 0; cf < 4; ++cf) {
                acc[rf][cf] = __builtin_amdgcn_mfma_f32_16x16x32_bf16(
                    ah[rf], bh[cur][cf], acc[rf][cf], 0, 0, 0);
                acc[rf][cf] = __builtin_amdgcn_mfma_f32_16x16x32_bf16(
                    ah[rf], bl[cur][cf], acc[rf][cf], 0, 0, 0);
                acc[rf][cf] = __builtin_amdgcn_mfma_f32_16x16x32_bf16(
                    al[rf], bh[cur][cf], acc[rf][cf], 0, 0, 0);
            }

        if (kc == 3) {
            const int kbase = cc * 128 + wc * 64 + c;
#pragma unroll
            for (int rf = 0; rf < 4; ++rf)
#pragma unroll
                for (int i = 0; i < 4; ++i) {
                    const int sidx = rf * 4 + i;
#pragma unroll
                    for (int cf = 0; cf < 4; ++cf) {
                        float v = acc[rf][cf][i];
                        int  kg = kbase + cf * 16;
                        if (v > bv[sidx]) { sv[sidx] = bv[sidx]; bv[sidx] = v; bk[sidx] = kg; }
                        else              { sv[sidx] = fmaxf(sv[sidx], v); }
                    }
                }
        }
    }

#pragma unroll
    for (int s = 0; s < 16; ++s) {
        float v1 = bv[s], v2 = sv[s]; int k1 = bk[s];
#pragma unroll
        for (int m = 1; m <= 8; m <<= 1) {
            float ov = __shfl_xor(v1, m, 64);
            float os = __shfl_xor(v2, m, 64);
            int   ok = __shfl_xor(k1, m, 64);
            if (ov > v1) { v2 = fmaxf(v1, os); v1 = ov; k1 = ok; }
            else         { v2 = fmaxf(v2, ov); }
        }
        bv[s] = v1; sv[s] = v2; bk[s] = k1;
    }

    __syncthreads();
    float* mv = (float*)lds;
    int*   mk = (int*)lds + 256;
    float* ms = (float*)lds + 512;
    if (c == 0) {
#pragma unroll
        for (int rf = 0; rf < 4; ++rf)
#pragma unroll
            for (int i = 0; i < 4; ++i) {
                int row = wr * 64 + rf * 16 + g * 4 + i;
                mv[wc * 128 + row] = bv[rf * 4 + i];
                mk[wc * 128 + row] = bk[rf * 4 + i];
                ms[wc * 128 + row] = sv[rf * 4 + i];
            }
    }
    __syncthreads();
    if (tid < 128) {
        float v1 = mv[tid], v2 = ms[tid]; int k1 = mk[tid];
        float ov = mv[128 + tid], os = ms[128 + tid]; int ok = mk[128 + tid];
        if (ov > v1) { v2 = fmaxf(v1, os); v1 = ov; k1 = ok; }
        else         { v2 = fmaxf(v2, ov); }
        assignv[r0 + tid] = k1;
        assign16[r0 + tid] = (unsigned short)k1;
        flags[r0 + tid] = (v1 - v2 < DELTA) ? 1 : 0;
    }
}

// ---------------------------------------------------------------------------
// Rescue: exact fp32 re-argmax (first-occurrence) for flagged rows only.
// ---------------------------------------------------------------------------
__global__ __launch_bounds__(256) void rescue_kernel(
    const float* __restrict__ E, const float* __restrict__ C,
    const unsigned char* __restrict__ flags,
    int* __restrict__ assignv, unsigned short* __restrict__ assign16)
{
    __shared__ int   rows[128];
    __shared__ int   nf;
    __shared__ float ev[DD];
    __shared__ float rv[4];
    __shared__ int   rk[4];

    const int tid  = threadIdx.x;
    const int base = blockIdx.x * 128;

    if (tid == 0) nf = 0;
    __syncthreads();
    if (tid < 128 && flags[base + tid]) {
        int p = atomicAdd(&nf, 1);
        rows[p] = base + tid;
    }
    __syncthreads();
    const int n = nf;
    if (n == 0) return;

    for (int i = 0; i < n; ++i) {
        const int row = rows[i];
        if (tid < 32)
            *(float4*)&ev[tid * 4] = *(const float4*)&E[(size_t)row * DD + tid * 4];
        __syncthreads();

        float d0 = 0.f, d1 = 0.f;
        for (int q = 0; q < 32; ++q) {
            float4 e4 = *(const float4*)&ev[q * 4];
            float4 c0 = *(const float4*)&C[(size_t)tid * DD + q * 4];
            float4 c1 = *(const float4*)&C[(size_t)(tid + 256) * DD + q * 4];
            d0 = fmaf(e4.x, c0.x, d0); d0 = fmaf(e4.y, c0.y, d0);
            d0 = fmaf(e4.z, c0.z, d0); d0 = fmaf(e4.w, c0.w, d0);
            d1 = fmaf(e4.x, c1.x, d1); d1 = fmaf(e4.y, c1.y, d1);
            d1 = fmaf(e4.z, c1.z, d1); d1 = fmaf(e4.w, c1.w, d1);
        }
        float v = (d0 >= d1) ? d0 : d1;
        int   k = (d0 >= d1) ? tid : tid + 256;
#pragma unroll
        for (int m = 1; m <= 32; m <<= 1) {
            float ov = __shfl_xor(v, m, 64);
            int   ok = __shfl_xor(k, m, 64);
            if (ov > v || (ov == v && ok < k)) { v = ov; k = ok; }
        }
        if ((tid & 63) == 0) { rv[tid >> 6] = v; rk[tid >> 6] = k; }
        __syncthreads();
        if (tid == 0) {
            float bv2 = rv[0]; int bk2 = rk[0];
#pragma unroll
            for (int w = 1; w < 4; ++w)
                if (rv[w] > bv2 || (rv[w] == bv2 && rk[w] < bk2)) { bv2 = rv[w]; bk2 = rk[w]; }
            assignv[row] = bk2;
            assign16[row] = (unsigned short)bk2;
        }
        __syncthreads();
    }
}

// ---------------------------------------------------------------------------
// Fallback assignment (pure fp32 VALU, verified) for tiny ws.
// ---------------------------------------------------------------------------
__global__ __launch_bounds__(256, 2) void assign_valu_kernel(
    const float* __restrict__ E, const float* __restrict__ C,
    int* __restrict__ assignv, unsigned short* __restrict__ assign16)
{
    __shared__ float smem[32 * SE + 32 * SC];
    float* ET = smem;
    float* CT = smem + 32 * SE;
    float* sval = smem;
    int*   sidx = ((int*)smem) + 32 * SS;

    const int tid = threadIdx.x;
    const int tx  = tid & 31;
    const int ty  = tid >> 5;
    const int r0  = blockIdx.x * 128;

    float bbv = 0.f;
    int   bbk = 0;

    for (int chunk = 0; chunk < 2; ++chunk) {
        const int k0 = chunk * 256;
        float acc[16][8];
#pragma unroll
        for (int i = 0; i < 16; ++i)
#pragma unroll
            for (int j = 0; j < 8; ++j) acc[i][j] = 0.f;

        for (int sub = 0; sub < 4; ++sub) {
            const int d0 = sub * 32;
            __syncthreads();
#pragma unroll
            for (int it = 0; it < 4; ++it) {
                int idx = tid + it * 256;
                int r = idx >> 3, q = idx & 7;
                float4 v = *(const float4*)&E[(r0 + r) * DD + d0 + q * 4];
                ET[(q * 4 + 0) * SE + r] = v.x;
                ET[(q * 4 + 1) * SE + r] = v.y;
                ET[(q * 4 + 2) * SE + r] = v.z;
                ET[(q * 4 + 3) * SE + r] = v.w;
            }
#pragma unroll
            for (int it = 0; it < 8; ++it) {
                int idx = tid + it * 256;
                int k = idx >> 3, q = idx & 7;
                float4 v = *(const float4*)&C[(k0 + k) * DD + d0 + q * 4];
                CT[(q * 4 + 0) * SC + k] = v.x;
                CT[(q * 4 + 1) * SC + k] = v.y;
                CT[(q * 4 + 2) * SC + k] = v.z;
                CT[(q * 4 + 3) * SC + k] = v.w;
            }
            __syncthreads();
#pragma unroll 4
            for (int d = 0; d < 32; ++d) {
                float4 a0 = *(const float4*)&ET[d * SE + ty * 16];
                float4 a1 = *(const float4*)&ET[d * SE + ty * 16 + 4];
                float4 a2 = *(const float4*)&ET[d * SE + ty * 16 + 8];
                float4 a3 = *(const float4*)&ET[d * SE + ty * 16 + 12];
                float4 b0 = *(const float4*)&CT[d * SC + tx * 4];
                float4 b1 = *(const float4*)&CT[d * SC + 128 + tx * 4];
                float ra[16] = {a0.x, a0.y, a0.z, a0.w, a1.x, a1.y, a1.z, a1.w,
                                a2.x, a2.y, a2.z, a2.w, a3.x, a3.y, a3.z, a3.w};
                float rb[8]  = {b0.x, b0.y, b0.z, b0.w, b1.x, b1.y, b1.z, b1.w};
#pragma unroll
                for (int i = 0; i < 16; ++i)
#pragma unroll
                    for (int j = 0; j < 8; ++j)
                        acc[i][j] = fmaf(ra[i], rb[j], acc[i][j]);
            }
        }
        __syncthreads();

#pragma unroll
        for (int i = 0; i < 16; ++i) {
            float bv = acc[i][0]; int bj = 0;
#pragma unroll
            for (int j = 1; j < 8; ++j)
                if (acc[i][j] > bv) { bv = acc[i][j]; bj = j; }
            int row = ty * 16 + i;
            int gk = k0 + ((bj < 4) ? (tx * 4 + bj) : (128 + tx * 4 + (bj - 4)));
            sval[tx * SS + row] = bv;
            sidx[tx * SS + row] = gk;
        }
        __syncthreads();
        if (tid < 128) {
            float bv = sval[tid]; int bi = sidx[tid];
            for (int t = 1; t < 32; ++t) {
                float v = sval[t * SS + tid];
                int   x = sidx[t * SS + tid];
                if (v > bv || (v == bv && x < bi)) { bv = v; bi = x; }
            }
            if (chunk == 0 || bv > bbv || (bv == bbv && bi < bbk)) {
                bbv = bv; bbk = bi;
            }
        }
    }
    if (tid < 128) {
        assignv[r0 + tid] = bbk;
        if (assign16) assign16[r0 + tid] = (unsigned short)bbk;
    }
}

// ---------------------------------------------------------------------------
// Fast M-step, phase 1: 2048 blocks = 4 per cluster. Deterministic.
// ---------------------------------------------------------------------------
__global__ __launch_bounds__(256) void update_partial_kernel(
    const float* __restrict__ E, const unsigned short* __restrict__ assign16,
    float* __restrict__ ws_sums, int* __restrict__ ws_cnts)
{
    const int b   = blockIdx.x;
    const int k   = b >> 2;
    const int qtr = b & 3;

    __shared__ float acc[4][DD];
    __shared__ int   cnts[4];

    const int tid  = threadIdx.x;
    const int w    = tid >> 6;
    const int lane = tid & 63;

    float a0 = 0.f, a1 = 0.f;
    int cnt = 0;
    const int wbase = qtr * (NN / 4) + w * (NN / 16);

    for (int it = 0; it < (NN / 16) / 512; ++it) {
        const int off = wbase + it * 512;
        uint4 p = *(const uint4*)&assign16[off + lane * 8];
        unsigned v[4] = {p.x, p.y, p.z, p.w};
#pragma unroll
        for (int h = 0; h < 4; ++h) {
            int lo = (int)(v[h] & 0xffffu);
            int hi = (int)(v[h] >> 16);
            unsigned long long mlo = __ballot(lo == k);
            unsigned long long mhi = __ballot(hi == k);
            cnt += (int)__popcll(mlo) + (int)__popcll(mhi);
            while (mlo) {
                int b2 = __ffsll((long long)mlo) - 1; mlo &= mlo - 1;
                int row = off + b2 * 8 + h * 2;
                float2 e = *(const float2*)&E[(size_t)row * DD + lane * 2];
                a0 += e.x; a1 += e.y;
            }
            while (mhi) {
                int b2 = __ffsll((long long)mhi) - 1; mhi &= mhi - 1;
                int row = off + b2 * 8 + h * 2 + 1;
                float2 e = *(const float2*)&E[(size_t)row * DD + lane * 2];
                a0 += e.x; a1 += e.y;
            }
        }
    }
    acc[w][lane * 2]     = a0;
    acc[w][lane * 2 + 1] = a1;
    if (lane == 0) cnts[w] = cnt;
    __syncthreads();
    if (tid < DD)
        ws_sums[(size_t)b * DD + tid] = acc[0][tid] + acc[1][tid] + acc[2][tid] + acc[3][tid];
    if (tid == 0)
        ws_cnts[b] = cnts[0] + cnts[1] + cnts[2] + cnts[3];
}

// ---------------------------------------------------------------------------
// Fast M-step, phase 2: combine 4 partials, mean, L2-normalize.
// ---------------------------------------------------------------------------
__global__ __launch_bounds__(128) void update_combine_kernel(
    const float* __restrict__ ws_sums, const int* __restrict__ ws_cnts,
    float* __restrict__ C)
{
    const int k = blockIdx.x, t = threadIdx.x;
    __shared__ float red[2];
    const int w = t >> 6, lane = t & 63;

    float s = ws_sums[(size_t)(4 * k + 0) * DD + t]
            + ws_sums[(size_t)(4 * k + 1) * DD + t]
            + ws_sums[(size_t)(4 * k + 2) * DD + t]
            + ws_sums[(size_t)(4 * k + 3) * DD + t];
    int cnt = ws_cnts[4 * k] + ws_cnts[4 * k + 1] + ws_cnts[4 * k + 2] + ws_cnts[4 * k + 3];
    float m = (cnt > 0) ? s / (float)cnt : C[k * DD + t];

    float sq = m * m;
#pragma unroll
    for (int o = 32; o > 0; o >>= 1) sq += __shfl_down(sq, o, 64);
    if (lane == 0) red[w] = sq;
    __syncthreads();
    float nrm = fmaxf(sqrtf(red[0] + red[1]), 1e-12f);
    C[k * DD + t] = m / nrm;
}

// ---------------------------------------------------------------------------
// Fallback M-step (no d_ws usage).
// ---------------------------------------------------------------------------
__global__ __launch_bounds__(256) void update_kernel(
    const float* __restrict__ E, const int* __restrict__ assignv,
    float* __restrict__ C)
{
    const int k = blockIdx.x;
    __shared__ float acc[4][DD];
    __shared__ int   cnts[4];
    __shared__ float red[4];

    const int tid  = threadIdx.x;
    const int w    = tid >> 6;
    const int lane = tid & 63;

    float a0 = 0.f, a1 = 0.f;
    int cnt = 0;
    const int per_wave = NN / 4;
    const int base = w * per_wave;

    for (int it = 0; it < per_wave / 256; ++it) {
        const int off = base + it * 256;
        int4 as = *(const int4*)&assignv[off + lane * 4];
        int av[4] = {as.x, as.y, as.z, as.w};
#pragma unroll
        for (int ci = 0; ci < 4; ++ci) {
            unsigned long long m = __ballot(av[ci] == k);
            cnt += (int)__popcll(m);
            while (m) {
                int b = __ffsll((long long)m) - 1;
                m &= m - 1;
                int r = off + b * 4 + ci;
                float2 v = *(const float2*)&E[r * DD + lane * 2];
                a0 += v.x; a1 += v.y;
            }
        }
    }
    acc[w][lane * 2]     = a0;
    acc[w][lane * 2 + 1] = a1;
    if (lane == 0) cnts[w] = cnt;
    __syncthreads();

    float m = 0.f;
    const int ctot = cnts[0] + cnts[1] + cnts[2] + cnts[3];
    if (tid < DD) {
        float s = acc[0][tid] + acc[1][tid] + acc[2][tid] + acc[3][tid];
        m = (ctot > 0) ? s / (float)ctot : C[k * DD + tid];
    }
    float sq = m * m;
#pragma unroll
    for (int o = 32; o > 0; o >>= 1) sq += __shfl_down(sq, o, 64);
    if (lane == 0) red[w] = sq;
    __syncthreads();
    if (tid < DD) {
        float nrm = fmaxf(sqrtf(red[0] + red[1]), 1e-12f);
        C[k * DD + tid] = m / nrm;
    }
}

__global__ void finalize_kernel(float* __restrict__ out)
{
    int i = blockIdx.x * 256 + threadIdx.x;
    if (i < NN) {
        int a = ((const int*)out)[i];
        out[i] = (float)a;
    }
}

extern "C" void kernel_launch(void* const* d_in, const int* in_sizes, int n_in,
                              void* d_out, int out_size, void* d_ws, size_t ws_size,
                              hipStream_t stream)
{
    (void)in_sizes; (void)n_in; (void)out_size;

    const float* E  = (const float*)d_in[0];
    const float* C0 = (const float*)d_in[1];
    // num_iters (d_in[2]) is a fixed scalar = 5; hardcoded (graph-safe).

    float* out     = (float*)d_out;
    float* C       = out + NN;        // centroids in d_out tail
    int*   assignv = (int*)out;       // assign ints in d_out head

    const bool fast  = (ws_size >= (size_t)WS_NEEDED);
    const bool fast2 = (ws_size >= (size_t)WS_NEEDED2);
    unsigned short* assign16 = fast ? (unsigned short*)d_ws : nullptr;
    float* ws_sums = fast ? (float*)((char*)d_ws + WS_SUMS_OFF) : nullptr;
    int*   ws_cnts = fast ? (int*)((char*)d_ws + WS_CNTS_OFF) : nullptr;
    unsigned char* flags = fast ? (unsigned char*)d_ws + WS_SUMS_OFF : nullptr;
    unsigned short* CH = fast ? (unsigned short*)((char*)d_ws + WS_CH_OFF) : nullptr;
    unsigned short* CL = fast ? (unsigned short*)((char*)d_ws + WS_CL_OFF) : nullptr;
    unsigned short* EAB = fast2 ? (unsigned short*)((char*)d_ws + WS_EAB3_OFF) : nullptr;

    hipMemcpyAsync(C, C0, (size_t)KK * DD * sizeof(float),
                   hipMemcpyDeviceToDevice, stream);

    if (fast2)
        presplit_e3_kernel<<<16384, 256, 0, stream>>>(E, EAB);

    for (int it = 0; it < NITER; ++it) {
        if (fast2) {
            split_c3_kernel<<<KK * DD / 4 / 256, 256, 0, stream>>>(C, CH, CL);
            assign4_kernel<<<NN / 128, 256, 0, stream>>>(EAB, CH, CL,
                                                         assignv, assign16, flags);
            rescue_kernel<<<NN / 128, 256, 0, stream>>>(E, C, flags, assignv, assign16);
            update_partial_kernel<<<2048, 256, 0, stream>>>(E, assign16, ws_sums, ws_cnts);
            update_combine_kernel<<<KK, 128, 0, stream>>>(ws_sums, ws_cnts, C);
        } else if (fast) {
            split_c_kernel<<<KK * DD / 4 / 256, 256, 0, stream>>>(C, CH, CL);
            assign_kernel<<<NN / 128, 256, 0, stream>>>(E, CH, CL, assignv, assign16, flags);
            rescue_kernel<<<NN / 128, 256, 0, stream>>>(E, C, flags, assignv, assign16);
            update_partial_kernel<<<2048, 256, 0, stream>>>(E, assign16, ws_sums, ws_cnts);
            update_combine_kernel<<<KK, 128, 0, stream>>>(ws_sums, ws_cnts, C);
        } else {
            assign_valu_kernel<<<NN / 128, 256, 0, stream>>>(E, C, assignv, nullptr);
            update_kernel<<<KK, 256, 0, stream>>>(E, assignv, C);
        }
    }
    finalize_kernel<<<(NN + 255) / 256, 256, 0, stream>>>(out);
}

// Round 9
// 1253.422 us; speedup vs baseline: 1.3101x; 1.0938x over previous
//
#include <hip/hip_runtime.h>

#define NN 262144   // rows (embeddings)
#define DD 128      // dim
#define KK 512      // clusters
#define NITER 5

// LDS row stride (bf16 elems) for fallback assign
#define SKH 136

// VALU-fallback LDS strides (floats)
#define SE 132
#define SC 260
#define SS 129

// Ambiguity threshold for the bf16x3 approx argmax. Rigorous error bound:
// 3*2^-16*||e||*||c|| <= 6.6e-4. delta = 2e-3 > 2*eps. (round-2 verified)
#define DELTA 2e-3f

// ---- workspace layout ----
#define WS_A16_BYTES   (NN * 2)                       // u16 assigns
#define WS_SUMS_OFF    (WS_A16_BYTES)                 // 2048 x 128 f32 partials
#define WS_CNTS_OFF    (WS_SUMS_OFF + 2048 * DD * 4)  // 2048 i32 counts
#define WS_NEEDED      (WS_CNTS_OFF + 2048 * 4)       // = 1581056 (round-2 gate)
// Overlays INSIDE ws_sums (1 MB), no lifetime overlap per iteration:
//   flags: NN bytes @ WS_SUMS_OFF       (assign writes -> rescue reads)
//   CH/CL fragment-major @ WS_SUMS_OFF + NN (split writes -> assign reads)
#define WS_CH_OFF      (WS_SUMS_OFF + NN)
#define WS_CL_OFF      (WS_CH_OFF + KK * DD * 2)
// fast2: pre-split E in 32-row-wave fragment-major units (EAB3, round-8 verified).
#define WS_EAB3_OFF    (WS_NEEDED)
#define WS_EAB3_BYTES  (NN * DD * 4)                  // 134217728
#define WS_NEEDED2     (WS_EAB3_OFF + WS_EAB3_BYTES)  // same gate as rounds 5-8

using s8     = __attribute__((ext_vector_type(8))) short;   // 8 bf16 (4 VGPR)
using f32x4  = __attribute__((ext_vector_type(4))) float;
using f32x16 = __attribute__((ext_vector_type(16))) float;  // 32x32 MFMA acc

// RNE float -> bf16 bits (finite inputs only)
__device__ __forceinline__ unsigned f2bf(float x) {
    unsigned u = __float_as_uint(x);
    return (u + 0x7fffu + ((u >> 16) & 1u)) >> 16;
}

// split float4 into packed hi/lo bf16 pairs (x = hi + lo + O(2^-16 x))
__device__ __forceinline__ void split4(float4 v, uint2& h, uint2& s) {
    unsigned hx = f2bf(v.x), hy = f2bf(v.y), hz = f2bf(v.z), hw = f2bf(v.w);
    float rx = v.x - __uint_as_float(hx << 16);
    float ry = v.y - __uint_as_float(hy << 16);
    float rz = v.z - __uint_as_float(hz << 16);
    float rw = v.w - __uint_as_float(hw << 16);
    unsigned lx = f2bf(rx), ly = f2bf(ry), lz = f2bf(rz), lw = f2bf(rw);
    h.x = hx | (hy << 16); h.y = hz | (hw << 16);
    s.x = lx | (ly << 16); s.y = lz | (lw << 16);
}

// ---------------------------------------------------------------------------
// ONE-TIME: pre-split E into EAB3 (32-row wave units), round-8 verified.
// ---------------------------------------------------------------------------
__global__ __launch_bounds__(256) void presplit_e3_kernel(
    const float* __restrict__ E, unsigned short* __restrict__ EAB)
{
    const int u   = blockIdx.x * 4 + (threadIdx.x >> 6);  // 0..65535
    const int l   = threadIdx.x & 63;
    const int g32 = u >> 3, ks = u & 7;
    const int row = g32 * 32 + (l & 31);
    const int k0  = ks * 16 + (l >> 5) * 8;
    float4 v0 = *(const float4*)&E[(size_t)row * DD + k0];
    float4 v1 = *(const float4*)&E[(size_t)row * DD + k0 + 4];
    uint2 h0, s0, h1, s1;
    split4(v0, h0, s0); split4(v1, h1, s1);
    size_t base = (size_t)u * 2048 + l * 16;
    *(uint2*)((char*)EAB + base)        = h0;
    *(uint2*)((char*)EAB + base + 8)    = h1;
    *(uint2*)((char*)EAB + base + 1024) = s0;
    *(uint2*)((char*)EAB + base + 1032) = s1;
}

// ---------------------------------------------------------------------------
// Per-iter split of C for the 32x32x16 B-fragment layout (round-7 verified).
// ---------------------------------------------------------------------------
__global__ __launch_bounds__(256) void split_c3_kernel(
    const float* __restrict__ C, unsigned short* __restrict__ CH,
    unsigned short* __restrict__ CL)
{
    int idx = blockIdx.x * 256 + threadIdx.x;      // 16384 float4s
    int col = idx >> 5;
    int k4  = (idx & 31) << 2;
    float4 v = *(const float4*)&C[(size_t)col * DD + k4];
    uint2 h, s;
    split4(v, h, s);
    int unit = (col >> 5) * 8 + (k4 >> 4);
    int lane = (col & 31) + ((k4 >> 3) & 1) * 32;
    int off  = unit * 512 + lane * 8 + (k4 & 7);
    *(uint2*)&CH[off] = h;
    *(uint2*)&CL[off] = s;
}

// ---------------------------------------------------------------------------
// FAST2 assign v5: bf16x3 GEMM on mfma_f32_32x32x16_bf16, A in registers
// (round-8 verified EAB3 load), B staged through DOUBLE-BUFFERED LDS
// half-chunks (32 KB each; 64 KB LDS -> 2 blocks/CU). Per half-chunk hc
// (2 col-frags x full K): issue next half's global loads early (T14),
// compute 8 ks-steps from LDS (conflict-free sequential ds_read_b128),
// fold top-2, ds_write prefetched regs, barrier. kg = hc*64+cfi*32+j is
// globally ascending per row -> first-occurrence semantics preserved.
// Epilogue/flags identical to round-7/8 verified path.
// ---------------------------------------------------------------------------
__global__ __launch_bounds__(256, 2) void assign5_kernel(
    const unsigned short* __restrict__ EAB,
    const unsigned short* __restrict__ CH, const unsigned short* __restrict__ CL,
    int* __restrict__ assignv, unsigned short* __restrict__ assign16,
    unsigned char* __restrict__ flags)
{
    __shared__ char bld[2][32768];     // [buf][hi 16KB | lo 16KB]

    const int tid = threadIdx.x;
    const int l   = tid & 63;
    const int wid = tid >> 6;
    const int j   = l & 31;            // A row / B col / D col within frag
    const int h   = l >> 5;            // k-octet half; D row offset 4*h
    const int r0  = blockIdx.x * 128;
    const int g32 = blockIdx.x * 4 + wid;

    // ---- load this wave's entire A tile into registers (16 x 1KB segments)
    const char* Abase = (const char*)EAB + (size_t)g32 * 16384 + l * 16;
    s8 Ah[8], Al[8];
#pragma unroll
    for (int ks = 0; ks < 8; ++ks) {
        Ah[ks] = *(const s8*)(Abase + ks * 2048);
        Al[ks] = *(const s8*)(Abase + ks * 2048 + 1024);
    }

    float bv[16], sv[16];
    int   bk[16];
#pragma unroll
    for (int i = 0; i < 16; ++i) { bv[i] = -3.4e38f; sv[i] = -3.4e38f; bk[i] = 0; }

    // ---- stage half-chunk 0 into buf 0 (hc base byte in CH/CL = hc*16384)
    {
        uint4 rH[4], rL[4];
#pragma unroll
        for (int p = 0; p < 4; ++p) {
            rH[p] = *(const uint4*)((const char*)CH + (p * 256 + tid) * 16);
            rL[p] = *(const uint4*)((const char*)CL + (p * 256 + tid) * 16);
        }
#pragma unroll
        for (int p = 0; p < 4; ++p) {
            *(uint4*)(bld[0] + (p * 256 + tid) * 16)         = rH[p];
            *(uint4*)(bld[0] + 16384 + (p * 256 + tid) * 16) = rL[p];
        }
    }
    __syncthreads();

#pragma unroll
    for (int hc = 0; hc < 8; ++hc) {
        const int cur = hc & 1, nxt = cur ^ 1;

        // prefetch next half-chunk into regs (loads fly under compute)
        uint4 rH[4], rL[4];
        if (hc < 7) {
            const char* srcH = (const char*)CH + (hc + 1) * 16384;
            const char* srcL = (const char*)CL + (hc + 1) * 16384;
#pragma unroll
            for (int p = 0; p < 4; ++p) {
                rH[p] = *(const uint4*)(srcH + (p * 256 + tid) * 16);
                rL[p] = *(const uint4*)(srcL + (p * 256 + tid) * 16);
            }
        }

        // compute this half-chunk: 2 col-frags x 8 ks-steps
        f32x16 acc[2];
#pragma unroll
        for (int cfi = 0; cfi < 2; ++cfi)
#pragma unroll
            for (int r = 0; r < 16; ++r) acc[cfi][r] = 0.f;

#pragma unroll
        for (int ks = 0; ks < 8; ++ks) {
#pragma unroll
            for (int cfi = 0; cfi < 2; ++cfi) {
                const int uu = cfi * 8 + ks;
                s8 bh = *(const s8*)(bld[cur] + uu * 1024 + l * 16);
                s8 bl = *(const s8*)(bld[cur] + 16384 + uu * 1024 + l * 16);
                acc[cfi] = __builtin_amdgcn_mfma_f32_32x32x16_bf16(
                    Ah[ks], bh, acc[cfi], 0, 0, 0);
                acc[cfi] = __builtin_amdgcn_mfma_f32_32x32x16_bf16(
                    Ah[ks], bl, acc[cfi], 0, 0, 0);
                acc[cfi] = __builtin_amdgcn_mfma_f32_32x32x16_bf16(
                    Al[ks], bh, acc[cfi], 0, 0, 0);
            }
        }

        // fold into per-lane running top-2 (kg ascending: hc outer, cfi inner)
#pragma unroll
        for (int cfi = 0; cfi < 2; ++cfi) {
            const int kg = hc * 64 + cfi * 32 + j;
#pragma unroll
            for (int r = 0; r < 16; ++r) {
                float v = acc[cfi][r];
                if (v > bv[r]) { sv[r] = bv[r]; bv[r] = v; bk[r] = kg; }
                else           { sv[r] = fmaxf(sv[r], v); }
            }
        }

        // write prefetched regs into the other buffer, then sync
        if (hc < 7) {
#pragma unroll
            for (int p = 0; p < 4; ++p) {
                *(uint4*)(bld[nxt] + (p * 256 + tid) * 16)         = rH[p];
                *(uint4*)(bld[nxt] + 16384 + (p * 256 + tid) * 16) = rL[p];
            }
            __syncthreads();
        }
    }

    // cross-lane top-2 butterfly over the 32 column-lanes of each half
#pragma unroll
    for (int r = 0; r < 16; ++r) {
        float v1 = bv[r], v2 = sv[r]; int k1 = bk[r];
#pragma unroll
        for (int m = 1; m <= 16; m <<= 1) {
            float ov = __shfl_xor(v1, m, 64);
            float os = __shfl_xor(v2, m, 64);
            int   ok = __shfl_xor(k1, m, 64);
            if (ov > v1) { v2 = fmaxf(v1, os); v1 = ov; k1 = ok; }
            else         { v2 = fmaxf(v2, ov); }
        }
        bv[r] = v1; sv[r] = v2; bk[r] = k1;
    }

    // epilogue: lane j==r writes row (r&3)+8*(r>>2)+4*h of its wave's 32 rows
#pragma unroll
    for (int r = 0; r < 16; ++r) {
        if (j == r) {
            int rowg = r0 + wid * 32 + (r & 3) + 8 * (r >> 2) + 4 * h;
            assignv[rowg]  = bk[r];
            assign16[rowg] = (unsigned short)bk[r];
            flags[rowg]    = (bv[r] - sv[r] < DELTA) ? 1 : 0;
        }
    }
}

// ---------------------------------------------------------------------------
// Per-iter split of C into hi/lo, 16x16 fragment-major (fast-path fallback).
// ---------------------------------------------------------------------------
__global__ __launch_bounds__(256) void split_c_kernel(
    const float* __restrict__ C, unsigned short* __restrict__ CH,
    unsigned short* __restrict__ CL)
{
    int idx = blockIdx.x * 256 + threadIdx.x;      // 16384 float4s
    int col = idx >> 5;
    int k4  = (idx & 31) << 2;
    float4 v = *(const float4*)&C[(size_t)col * DD + k4];
    uint2 h, s;
    split4(v, h, s);
    int group = (col >> 4) * 4 + (k4 >> 5);
    int inner = ((k4 >> 3) & 3) * 16 + (col & 15);
    int off   = group * 512 + inner * 8 + (k4 & 7);
    *(uint2*)&CH[off] = h;
    *(uint2*)&CL[off] = s;
}

// ---------------------------------------------------------------------------
// Fallback fast assign (round-4 verified): split E in-kernel, B from CH/CL.
// ---------------------------------------------------------------------------
__global__ __launch_bounds__(256, 2) void assign_kernel(
    const float* __restrict__ E,
    const unsigned short* __restrict__ CH, const unsigned short* __restrict__ CL,
    int* __restrict__ assignv, unsigned short* __restrict__ assign16,
    unsigned char* __restrict__ flags)
{
    __shared__ unsigned short lds[2 * 128 * SKH];   // 69632 B
    unsigned short* EH = lds;
    unsigned short* EL = lds + 128 * SKH;

    const int tid = threadIdx.x;
    const int l   = tid & 63;
    const int wid = tid >> 6;
    const int wr  = wid >> 1;
    const int wc  = wid & 1;
    const int c   = l & 15;
    const int g   = l >> 4;
    const int r0  = blockIdx.x * 128;

#pragma unroll
    for (int it = 0; it < 16; ++it) {
        int idx = it * 256 + tid;
        int row = idx >> 5;
        int k4  = (idx & 31) << 2;
        float4 v = *(const float4*)&E[(size_t)(r0 + row) * DD + k4];
        uint2 h, s;
        split4(v, h, s);
        *(uint2*)&EH[row * SKH + k4] = h;
        *(uint2*)&EL[row * SKH + k4] = s;
    }
    __syncthreads();

    float bv[16], sv[16];
    int   bk[16];
#pragma unroll
    for (int i = 0; i < 16; ++i) { bv[i] = -3.4e38f; sv[i] = -3.4e38f; bk[i] = 0; }

    const int aoff0 = (wr * 64 + c) * SKH + g * 8;
    const int bbase = wc * 16 * 512 + l * 8;

    s8 bh[2][4], bl[2][4];
#pragma unroll
    for (int cf = 0; cf < 4; ++cf) {
        int off = bbase + (cf * 4) * 512;
        bh[0][cf] = *(const s8*)&CH[off];
        bl[0][cf] = *(const s8*)&CL[off];
    }

    f32x4 acc[4][4];

#pragma unroll
    for (int t = 0; t < 16; ++t) {
        const int cc  = t >> 2, kc = t & 3;
        const int cur = t & 1,  nxt = cur ^ 1;

        if (kc == 0) {
#pragma unroll
            for (int rf = 0; rf < 4; ++rf)
#pragma unroll
                for (int cf = 0; cf < 4; ++cf)
                    acc[rf][cf] = (f32x4){0.f, 0.f, 0.f, 0.f};
        }

        if (t < 15) {
            const int t1 = t + 1, cc1 = t1 >> 2, kc1 = t1 & 3;
#pragma unroll
            for (int cf = 0; cf < 4; ++cf) {
                int off = bbase + (cc1 * 32 + cf * 4 + kc1) * 512;
                bh[nxt][cf] = *(const s8*)&CH[off];
                bl[nxt][cf] = *(const s8*)&CL[off];
            }
        }

        s8 ah[4], al[4];
#pragma unroll
        for (int rf = 0; rf < 4; ++rf) {
            int off = aoff0 + rf * 16 * SKH + kc * 32;
            ah[rf] = *(const s8*)&EH[off];
            al[rf] = *(const s8*)&EL[off];
        }

#pragma unroll
        for (int rf = 0; rf < 4; ++rf)
#pragma unroll
            for (int cf = 0; cf < 4; ++cf) {
                acc[rf][cf] = __builtin_amdgcn_mfma_f32_16x16x32_bf16(
                    ah[rf], bh[cur][cf], acc[rf][cf], 0, 0, 0);
                acc[rf][cf] = __builtin_amdgcn_mfma_f32_16x16x32_bf16(
                    ah[rf], bl[cur][cf], acc[rf][cf], 0, 0, 0);
                acc[rf][cf] = __builtin_amdgcn_mfma_f32_16x16x32_bf16(
                    al[rf], bh[cur][cf], acc[rf][cf], 0, 0, 0);
            }

        if (kc == 3) {
            const int kbase = cc * 128 + wc * 64 + c;
#pragma unroll
            for (int rf = 0; rf < 4; ++rf)
#pragma unroll
                for (int i = 0; i < 4; ++i) {
                    const int sidx = rf * 4 + i;
#pragma unroll
                    for (int cf = 0; cf < 4; ++cf) {
                        float v = acc[rf][cf][i];
                        int  kg = kbase + cf * 16;
                        if (v > bv[sidx]) { sv[sidx] = bv[sidx]; bv[sidx] = v; bk[sidx] = kg; }
                        else              { sv[sidx] = fmaxf(sv[sidx], v); }
                    }
                }
        }
    }

#pragma unroll
    for (int s = 0; s < 16; ++s) {
        float v1 = bv[s], v2 = sv[s]; int k1 = bk[s];
#pragma unroll
        for (int m = 1; m <= 8; m <<= 1) {
            float ov = __shfl_xor(v1, m, 64);
            float os = __shfl_xor(v2, m, 64);
            int   ok = __shfl_xor(k1, m, 64);
            if (ov > v1) { v2 = fmaxf(v1, os); v1 = ov; k1 = ok; }
            else         { v2 = fmaxf(v2, ov); }
        }
        bv[s] = v1; sv[s] = v2; bk[s] = k1;
    }

    __syncthreads();
    float* mv = (float*)lds;
    int*   mk = (int*)lds + 256;
    float* ms = (float*)lds + 512;
    if (c == 0) {
#pragma unroll
        for (int rf = 0; rf < 4; ++rf)
#pragma unroll
            for (int i = 0; i < 4; ++i) {
                int row = wr * 64 + rf * 16 + g * 4 + i;
                mv[wc * 128 + row] = bv[rf * 4 + i];
                mk[wc * 128 + row] = bk[rf * 4 + i];
                ms[wc * 128 + row] = sv[rf * 4 + i];
            }
    }
    __syncthreads();
    if (tid < 128) {
        float v1 = mv[tid], v2 = ms[tid]; int k1 = mk[tid];
        float ov = mv[128 + tid], os = ms[128 + tid]; int ok = mk[128 + tid];
        if (ov > v1) { v2 = fmaxf(v1, os); v1 = ov; k1 = ok; }
        else         { v2 = fmaxf(v2, ov); }
        assignv[r0 + tid] = k1;
        assign16[r0 + tid] = (unsigned short)k1;
        flags[r0 + tid] = (v1 - v2 < DELTA) ? 1 : 0;
    }
}

// ---------------------------------------------------------------------------
// Rescue: exact fp32 re-argmax (first-occurrence) for flagged rows only.
// ---------------------------------------------------------------------------
__global__ __launch_bounds__(256) void rescue_kernel(
    const float* __restrict__ E, const float* __restrict__ C,
    const unsigned char* __restrict__ flags,
    int* __restrict__ assignv, unsigned short* __restrict__ assign16)
{
    __shared__ int   rows[128];
    __shared__ int   nf;
    __shared__ float ev[DD];
    __shared__ float rv[4];
    __shared__ int   rk[4];

    const int tid  = threadIdx.x;
    const int base = blockIdx.x * 128;

    if (tid == 0) nf = 0;
    __syncthreads();
    if (tid < 128 && flags[base + tid]) {
        int p = atomicAdd(&nf, 1);
        rows[p] = base + tid;
    }
    __syncthreads();
    const int n = nf;
    if (n == 0) return;

    for (int i = 0; i < n; ++i) {
        const int row = rows[i];
        if (tid < 32)
            *(float4*)&ev[tid * 4] = *(const float4*)&E[(size_t)row * DD + tid * 4];
        __syncthreads();

        float d0 = 0.f, d1 = 0.f;
        for (int q = 0; q < 32; ++q) {
            float4 e4 = *(const float4*)&ev[q * 4];
            float4 c0 = *(const float4*)&C[(size_t)tid * DD + q * 4];
            float4 c1 = *(const float4*)&C[(size_t)(tid + 256) * DD + q * 4];
            d0 = fmaf(e4.x, c0.x, d0); d0 = fmaf(e4.y, c0.y, d0);
            d0 = fmaf(e4.z, c0.z, d0); d0 = fmaf(e4.w, c0.w, d0);
            d1 = fmaf(e4.x, c1.x, d1); d1 = fmaf(e4.y, c1.y, d1);
            d1 = fmaf(e4.z, c1.z, d1); d1 = fmaf(e4.w, c1.w, d1);
        }
        float v = (d0 >= d1) ? d0 : d1;
        int   k = (d0 >= d1) ? tid : tid + 256;
#pragma unroll
        for (int m = 1; m <= 32; m <<= 1) {
            float ov = __shfl_xor(v, m, 64);
            int   ok = __shfl_xor(k, m, 64);
            if (ov > v || (ov == v && ok < k)) { v = ov; k = ok; }
        }
        if ((tid & 63) == 0) { rv[tid >> 6] = v; rk[tid >> 6] = k; }
        __syncthreads();
        if (tid == 0) {
            float bv2 = rv[0]; int bk2 = rk[0];
#pragma unroll
            for (int w = 1; w < 4; ++w)
                if (rv[w] > bv2 || (rv[w] == bv2 && rk[w] < bk2)) { bv2 = rv[w]; bk2 = rk[w]; }
            assignv[row] = bk2;
            assign16[row] = (unsigned short)bk2;
        }
        __syncthreads();
    }
}

// ---------------------------------------------------------------------------
// Fallback assignment (pure fp32 VALU, verified) for tiny ws.
// ---------------------------------------------------------------------------
__global__ __launch_bounds__(256, 2) void assign_valu_kernel(
    const float* __restrict__ E, const float* __restrict__ C,
    int* __restrict__ assignv, unsigned short* __restrict__ assign16)
{
    __shared__ float smem[32 * SE + 32 * SC];
    float* ET = smem;
    float* CT = smem + 32 * SE;
    float* sval = smem;
    int*   sidx = ((int*)smem) + 32 * SS;

    const int tid = threadIdx.x;
    const int tx  = tid & 31;
    const int ty  = tid >> 5;
    const int r0  = blockIdx.x * 128;

    float bbv = 0.f;
    int   bbk = 0;

    for (int chunk = 0; chunk < 2; ++chunk) {
        const int k0 = chunk * 256;
        float acc[16][8];
#pragma unroll
        for (int i = 0; i < 16; ++i)
#pragma unroll
            for (int j = 0; j < 8; ++j) acc[i][j] = 0.f;

        for (int sub = 0; sub < 4; ++sub) {
            const int d0 = sub * 32;
            __syncthreads();
#pragma unroll
            for (int it = 0; it < 4; ++it) {
                int idx = tid + it * 256;
                int r = idx >> 3, q = idx & 7;
                float4 v = *(const float4*)&E[(r0 + r) * DD + d0 + q * 4];
                ET[(q * 4 + 0) * SE + r] = v.x;
                ET[(q * 4 + 1) * SE + r] = v.y;
                ET[(q * 4 + 2) * SE + r] = v.z;
                ET[(q * 4 + 3) * SE + r] = v.w;
            }
#pragma unroll
            for (int it = 0; it < 8; ++it) {
                int idx = tid + it * 256;
                int k = idx >> 3, q = idx & 7;
                float4 v = *(const float4*)&C[(k0 + k) * DD + d0 + q * 4];
                CT[(q * 4 + 0) * SC + k] = v.x;
                CT[(q * 4 + 1) * SC + k] = v.y;
                CT[(q * 4 + 2) * SC + k] = v.z;
                CT[(q * 4 + 3) * SC + k] = v.w;
            }
            __syncthreads();
#pragma unroll 4
            for (int d = 0; d < 32; ++d) {
                float4 a0 = *(const float4*)&ET[d * SE + ty * 16];
                float4 a1 = *(const float4*)&ET[d * SE + ty * 16 + 4];
                float4 a2 = *(const float4*)&ET[d * SE + ty * 16 + 8];
                float4 a3 = *(const float4*)&ET[d * SE + ty * 16 + 12];
                float4 b0 = *(const float4*)&CT[d * SC + tx * 4];
                float4 b1 = *(const float4*)&CT[d * SC + 128 + tx * 4];
                float ra[16] = {a0.x, a0.y, a0.z, a0.w, a1.x, a1.y, a1.z, a1.w,
                                a2.x, a2.y, a2.z, a2.w, a3.x, a3.y, a3.z, a3.w};
                float rb[8]  = {b0.x, b0.y, b0.z, b0.w, b1.x, b1.y, b1.z, b1.w};
#pragma unroll
                for (int i = 0; i < 16; ++i)
#pragma unroll
                    for (int j = 0; j < 8; ++j)
                        acc[i][j] = fmaf(ra[i], rb[j], acc[i][j]);
            }
        }
        __syncthreads();

#pragma unroll
        for (int i = 0; i < 16; ++i) {
            float bv = acc[i][0]; int bj = 0;
#pragma unroll
            for (int j = 1; j < 8; ++j)
                if (acc[i][j] > bv) { bv = acc[i][j]; bj = j; }
            int row = ty * 16 + i;
            int gk = k0 + ((bj < 4) ? (tx * 4 + bj) : (128 + tx * 4 + (bj - 4)));
            sval[tx * SS + row] = bv;
            sidx[tx * SS + row] = gk;
        }
        __syncthreads();
        if (tid < 128) {
            float bv = sval[tid]; int bi = sidx[tid];
            for (int t = 1; t < 32; ++t) {
                float v = sval[t * SS + tid];
                int   x = sidx[t * SS + tid];
                if (v > bv || (v == bv && x < bi)) { bv = v; bi = x; }
            }
            if (chunk == 0 || bv > bbv || (bv == bbv && bi < bbk)) {
                bbv = bv; bbk = bi;
            }
        }
    }
    if (tid < 128) {
        assignv[r0 + tid] = bbk;
        if (assign16) assign16[r0 + tid] = (unsigned short)bbk;
    }
}

// ---------------------------------------------------------------------------
// Fast M-step, phase 1: 2048 blocks = 4 per cluster. Deterministic.
// ---------------------------------------------------------------------------
__global__ __launch_bounds__(256) void update_partial_kernel(
    const float* __restrict__ E, const unsigned short* __restrict__ assign16,
    float* __restrict__ ws_sums, int* __restrict__ ws_cnts)
{
    const int b   = blockIdx.x;
    const int k   = b >> 2;
    const int qtr = b & 3;

    __shared__ float acc[4][DD];
    __shared__ int   cnts[4];

    const int tid  = threadIdx.x;
    const int w    = tid >> 6;
    const int lane = tid & 63;

    float a0 = 0.f, a1 = 0.f;
    int cnt = 0;
    const int wbase = qtr * (NN / 4) + w * (NN / 16);

    for (int it = 0; it < (NN / 16) / 512; ++it) {
        const int off = wbase + it * 512;
        uint4 p = *(const uint4*)&assign16[off + lane * 8];
        unsigned v[4] = {p.x, p.y, p.z, p.w};
#pragma unroll
        for (int h = 0; h < 4; ++h) {
            int lo = (int)(v[h] & 0xffffu);
            int hi = (int)(v[h] >> 16);
            unsigned long long mlo = __ballot(lo == k);
            unsigned long long mhi = __ballot(hi == k);
            cnt += (int)__popcll(mlo) + (int)__popcll(mhi);
            while (mlo) {
                int b2 = __ffsll((long long)mlo) - 1; mlo &= mlo - 1;
                int row = off + b2 * 8 + h * 2;
                float2 e = *(const float2*)&E[(size_t)row * DD + lane * 2];
                a0 += e.x; a1 += e.y;
            }
            while (mhi) {
                int b2 = __ffsll((long long)mhi) - 1; mhi &= mhi - 1;
                int row = off + b2 * 8 + h * 2 + 1;
                float2 e = *(const float2*)&E[(size_t)row * DD + lane * 2];
                a0 += e.x; a1 += e.y;
            }
        }
    }
    acc[w][lane * 2]     = a0;
    acc[w][lane * 2 + 1] = a1;
    if (lane == 0) cnts[w] = cnt;
    __syncthreads();
    if (tid < DD)
        ws_sums[(size_t)b * DD + tid] = acc[0][tid] + acc[1][tid] + acc[2][tid] + acc[3][tid];
    if (tid == 0)
        ws_cnts[b] = cnts[0] + cnts[1] + cnts[2] + cnts[3];
}

// ---------------------------------------------------------------------------
// Fast M-step, phase 2: combine 4 partials, mean, L2-normalize.
// ---------------------------------------------------------------------------
__global__ __launch_bounds__(128) void update_combine_kernel(
    const float* __restrict__ ws_sums, const int* __restrict__ ws_cnts,
    float* __restrict__ C)
{
    const int k = blockIdx.x, t = threadIdx.x;
    __shared__ float red[2];
    const int w = t >> 6, lane = t & 63;

    float s = ws_sums[(size_t)(4 * k + 0) * DD + t]
            + ws_sums[(size_t)(4 * k + 1) * DD + t]
            + ws_sums[(size_t)(4 * k + 2) * DD + t]
            + ws_sums[(size_t)(4 * k + 3) * DD + t];
    int cnt = ws_cnts[4 * k] + ws_cnts[4 * k + 1] + ws_cnts[4 * k + 2] + ws_cnts[4 * k + 3];
    float m = (cnt > 0) ? s / (float)cnt : C[k * DD + t];

    float sq = m * m;
#pragma unroll
    for (int o = 32; o > 0; o >>= 1) sq += __shfl_down(sq, o, 64);
    if (lane == 0) red[w] = sq;
    __syncthreads();
    float nrm = fmaxf(sqrtf(red[0] + red[1]), 1e-12f);
    C[k * DD + t] = m / nrm;
}

// ---------------------------------------------------------------------------
// Fallback M-step (no d_ws usage).
// ---------------------------------------------------------------------------
__global__ __launch_bounds__(256) void update_kernel(
    const float* __restrict__ E, const int* __restrict__ assignv,
    float* __restrict__ C)
{
    const int k = blockIdx.x;
    __shared__ float acc[4][DD];
    __shared__ int   cnts[4];
    __shared__ float red[4];

    const int tid  = threadIdx.x;
    const int w    = tid >> 6;
    const int lane = tid & 63;

    float a0 = 0.f, a1 = 0.f;
    int cnt = 0;
    const int per_wave = NN / 4;
    const int base = w * per_wave;

    for (int it = 0; it < per_wave / 256; ++it) {
        const int off = base + it * 256;
        int4 as = *(const int4*)&assignv[off + lane * 4];
        int av[4] = {as.x, as.y, as.z, as.w};
#pragma unroll
        for (int ci = 0; ci < 4; ++ci) {
            unsigned long long m = __ballot(av[ci] == k);
            cnt += (int)__popcll(m);
            while (m) {
                int b = __ffsll((long long)m) - 1;
                m &= m - 1;
                int r = off + b * 4 + ci;
                float2 v = *(const float2*)&E[r * DD + lane * 2];
                a0 += v.x; a1 += v.y;
            }
        }
    }
    acc[w][lane * 2]     = a0;
    acc[w][lane * 2 + 1] = a1;
    if (lane == 0) cnts[w] = cnt;
    __syncthreads();

    float m = 0.f;
    const int ctot = cnts[0] + cnts[1] + cnts[2] + cnts[3];
    if (tid < DD) {
        float s = acc[0][tid] + acc[1][tid] + acc[2][tid] + acc[3][tid];
        m = (ctot > 0) ? s / (float)ctot : C[k * DD + tid];
    }
    float sq = m * m;
#pragma unroll
    for (int o = 32; o > 0; o >>= 1) sq += __shfl_down(sq, o, 64);
    if (lane == 0) red[w] = sq;
    __syncthreads();
    if (tid < DD) {
        float nrm = fmaxf(sqrtf(red[0] + red[1]), 1e-12f);
        C[k * DD + tid] = m / nrm;
    }
}

__global__ void finalize_kernel(float* __restrict__ out)
{
    int i = blockIdx.x * 256 + threadIdx.x;
    if (i < NN) {
        int a = ((const int*)out)[i];
        out[i] = (float)a;
    }
}

extern "C" void kernel_launch(void* const* d_in, const int* in_sizes, int n_in,
                              void* d_out, int out_size, void* d_ws, size_t ws_size,
                              hipStream_t stream)
{
    (void)in_sizes; (void)n_in; (void)out_size;

    const float* E  = (const float*)d_in[0];
    const float* C0 = (const float*)d_in[1];
    // num_iters (d_in[2]) is a fixed scalar = 5; hardcoded (graph-safe).

    float* out     = (float*)d_out;
    float* C       = out + NN;        // centroids in d_out tail
    int*   assignv = (int*)out;       // assign ints in d_out head

    const bool fast  = (ws_size >= (size_t)WS_NEEDED);
    const bool fast2 = (ws_size >= (size_t)WS_NEEDED2);
    unsigned short* assign16 = fast ? (unsigned short*)d_ws : nullptr;
    float* ws_sums = fast ? (float*)((char*)d_ws + WS_SUMS_OFF) : nullptr;
    int*   ws_cnts = fast ? (int*)((char*)d_ws + WS_CNTS_OFF) : nullptr;
    unsigned char* flags = fast ? (unsigned char*)d_ws + WS_SUMS_OFF : nullptr;
    unsigned short* CH = fast ? (unsigned short*)((char*)d_ws + WS_CH_OFF) : nullptr;
    unsigned short* CL = fast ? (unsigned short*)((char*)d_ws + WS_CL_OFF) : nullptr;
    unsigned short* EAB = fast2 ? (unsigned short*)((char*)d_ws + WS_EAB3_OFF) : nullptr;

    hipMemcpyAsync(C, C0, (size_t)KK * DD * sizeof(float),
                   hipMemcpyDeviceToDevice, stream);

    if (fast2)
        presplit_e3_kernel<<<16384, 256, 0, stream>>>(E, EAB);

    for (int it = 0; it < NITER; ++it) {
        if (fast2) {
            split_c3_kernel<<<KK * DD / 4 / 256, 256, 0, stream>>>(C, CH, CL);
            assign5_kernel<<<NN / 128, 256, 0, stream>>>(EAB, CH, CL,
                                                         assignv, assign16, flags);
            rescue_kernel<<<NN / 128, 256, 0, stream>>>(E, C, flags, assignv, assign16);
            update_partial_kernel<<<2048, 256, 0, stream>>>(E, assign16, ws_sums, ws_cnts);
            update_combine_kernel<<<KK, 128, 0, stream>>>(ws_sums, ws_cnts, C);
        } else if (fast) {
            split_c_kernel<<<KK * DD / 4 / 256, 256, 0, stream>>>(C, CH, CL);
            assign_kernel<<<NN / 128, 256, 0, stream>>>(E, CH, CL, assignv, assign16, flags);
            rescue_kernel<<<NN / 128, 256, 0, stream>>>(E, C, flags, assignv, assign16);
            update_partial_kernel<<<2048, 256, 0, stream>>>(E, assign16, ws_sums, ws_cnts);
            update_combine_kernel<<<KK, 128, 0, stream>>>(ws_sums, ws_cnts, C);
        } else {
            assign_valu_kernel<<<NN / 128, 256, 0, stream>>>(E, C, assignv, nullptr);
            update_kernel<<<KK, 256, 0, stream>>>(E, assignv, C);
        }
    }
    finalize_kernel<<<(NN + 255) / 256, 256, 0, stream>>>(out);
}